// Round 2
// baseline (2153.144 us; speedup 1.0000x reference)
//
#include <hip/hip_runtime.h>
#include <hip/hip_bf16.h>
#include <math.h>

#define Bb 64
#define Ss 30
#define Cc 62
#define Ll 169
#define CL (Cc*Ll)          // 10478
#define GRU 64

// ---------------- K1: sq[b,s] = mean over (c,L) ----------------
__global__ __launch_bounds__(256) void k_sq(const float* __restrict__ x, float* __restrict__ sq)
{
    __shared__ float red[4];
    int bs = blockIdx.x;
    const float* p = x + (size_t)bs * CL;
    float acc = 0.f;
    for (int i = threadIdx.x; i < CL; i += 256) acc += p[i];
    for (int off = 32; off; off >>= 1) acc += __shfl_down(acc, off);
    if ((threadIdx.x & 63) == 0) red[threadIdx.x >> 6] = acc;
    __syncthreads();
    if (threadIdx.x == 0) sq[bs] = (red[0] + red[1] + red[2] + red[3]) / (float)CL;
}

// ---------------- K2: SE MLP -> a[b,s] ----------------
__global__ __launch_bounds__(64) void k_se(const float* __restrict__ sq, const float* __restrict__ w1,
                                           const float* __restrict__ w2, float* __restrict__ aout)
{
    int b = threadIdx.x;
    float sv[Ss];
#pragma unroll
    for (int s = 0; s < Ss; ++s) sv[s] = sq[b*Ss + s];
    float hid[15];
#pragma unroll
    for (int j = 0; j < 15; ++j) {
        float h = 0.f;
#pragma unroll
        for (int s = 0; s < Ss; ++s) h += sv[s] * w1[s*15 + j];
        hid[j] = fmaxf(h, 0.f);
    }
#pragma unroll
    for (int s = 0; s < Ss; ++s) {
        float o = 0.f;
#pragma unroll
        for (int j = 0; j < 15; ++j) o += hid[j] * w2[j*Ss + s];
        aout[b*Ss + s] = 1.f / (1.f + expf(-o));
    }
}

// ---------------- K3: max_seg[b,c,l] = max_s a[b,s]*x[b,s,c,l] ----------------
__global__ __launch_bounds__(256) void k_maxseg(const float* __restrict__ x, const float* __restrict__ a,
                                                float* __restrict__ ms)
{
    int idx = blockIdx.x * 256 + threadIdx.x;
    if (idx >= Bb*CL) return;
    int b = idx / CL;
    int rem = idx - b*CL;
    float m = -INFINITY;
    for (int s = 0; s < Ss; ++s) {
        float v = x[(size_t)(b*Ss + s)*CL + rem] * a[b*Ss + s];
        m = fmaxf(m, v);
    }
    ms[idx] = m;
}

// ---------------- K4: direct DFT per (b,c) row ----------------
__global__ __launch_bounds__(256) void k_dft(const float* __restrict__ ms, float* __restrict__ fre,
                                             float* __restrict__ fim)
{
    __shared__ float xr[Ll], ct[Ll], st[Ll];
    int row = blockIdx.x;
    int tid = threadIdx.x;
    if (tid < Ll) {
        xr[tid] = ms[(size_t)row*Ll + tid];
        float ang = (float)tid * (6.28318530717958647692f / (float)Ll);
        ct[tid] = cosf(ang);
        st[tid] = sinf(ang);
    }
    __syncthreads();
    if (tid < Ll) {
        int k = tid;
        float re = 0.f, im = 0.f;
        int idx = 0;
        for (int n = 0; n < Ll; ++n) {
            float v = xr[n];
            re += v * ct[idx];
            im -= v * st[idx];
            idx += k; if (idx >= Ll) idx -= Ll;
        }
        fre[(size_t)row*Ll + k] = re;
        fim[(size_t)row*Ll + k] = im;
    }
}

// ---------------- K5: adj row 61 ----------------
__global__ __launch_bounds__(64) void k_adjrow(const float* __restrict__ fre, const float* __restrict__ fim,
                                               float* __restrict__ adjr)
{
    int b = blockIdx.x / Cc;
    int j = blockIdx.x % Cc;
    int lane = threadIdx.x;
    const float* re61 = fre + (size_t)(b*Cc + 61)*Ll;
    const float* im61 = fim + (size_t)(b*Cc + 61)*Ll;
    const float* rej  = fre + (size_t)(b*Cc + j)*Ll;
    const float* imj  = fim + (size_t)(b*Cc + j)*Ll;
    float num = 0.f, den = 0.f;
    for (int l = lane; l < Ll; l += 64) {
        float ar = re61[l], ai = im61[l];
        float br = rej[l],  bi = imj[l];
        num += ai*br - ar*bi;
        den += sqrtf(ar*ar + ai*ai) * sqrtf(br*br + bi*bi);
    }
    for (int off = 32; off; off >>= 1) { num += __shfl_down(num, off); den += __shfl_down(den, off); }
    if (lane == 0) adjr[b*Cc + j] = (j == 61) ? 0.f : num / den;
}

// ================= K6: fused dsc chain =================
// LDS layout:
//   X[10488]: input x row (stride 169), later z1 (stride 109), z2 (stride 81)
//   A[6704] : y1 (stride 108), y2 (stride 84), y3 (stride 68) -- mult-of-4 for float4 reads
//   W[1984] : current stage weight (half-)tile, layout Wt[k*62 + m] / Wt[i*62 + o]

template<int NW>
__device__ __forceinline__ void dw_group(const float* __restrict__ xr, const float* __restrict__ wr,
                                         float& a0, float& a1, float& a2, float& a3,
                                         float& a4, float& a5, float& a6, float& a7)
{
    float xv[NW + 7];
#pragma unroll
    for (int j = 0; j < NW + 7; ++j) xv[j] = xr[j];
#pragma unroll
    for (int j = 0; j < NW; ++j) {
        float wk = wr[j * Cc];
        a0 += wk * xv[j + 0]; a1 += wk * xv[j + 1];
        a2 += wk * xv[j + 2]; a3 += wk * xv[j + 3];
        a4 += wk * xv[j + 4]; a5 += wk * xv[j + 5];
        a6 += wk * xv[j + 6]; a7 += wk * xv[j + 7];
    }
}

// MODE 0: dst = sum ; MODE 1: dst += sum + bias ; MODE 2: dst = sum + bias
template<int K, int SIN, int SOUT, int LOUT, int MODE>
__device__ __forceinline__ void dw_pass(const float* __restrict__ Xb, int k0,
                                        const float* __restrict__ Wh,
                                        const float* __restrict__ bias,
                                        float* __restrict__ Ab, int tid)
{
    constexpr int CH = (LOUT + 7) / 8;
    constexpr int NG = K / 8, REM = K % 8;
    for (int u = tid; u < Cc * CH; u += 512) {
        int m  = u % Cc;
        int p0 = (u / Cc) * 8;
        const float* xr = Xb + m * SIN + p0 + k0;
        const float* wr = Wh + m;
        float a0=0.f,a1=0.f,a2=0.f,a3=0.f,a4=0.f,a5=0.f,a6=0.f,a7=0.f;
#pragma unroll
        for (int g = 0; g < NG; ++g)
            dw_group<8>(xr + g*8, wr + g*8*Cc, a0,a1,a2,a3,a4,a5,a6,a7);
        if constexpr (REM > 0)
            dw_group<REM>(xr + NG*8, wr + NG*8*Cc, a0,a1,a2,a3,a4,a5,a6,a7);
        float* dst = Ab + m * SOUT + p0;
        float r[8] = {a0,a1,a2,a3,a4,a5,a6,a7};
        if constexpr (MODE == 0) {
#pragma unroll
            for (int q = 0; q < 8; ++q) if (p0 + q < LOUT) dst[q] = r[q];
        } else if constexpr (MODE == 1) {
            float bm = bias[m];
#pragma unroll
            for (int q = 0; q < 8; ++q) if (p0 + q < LOUT) dst[q] = dst[q] + r[q] + bm;
        } else {
            float bm = bias[m];
#pragma unroll
            for (int q = 0; q < 8; ++q) if (p0 + q < LOUT) dst[q] = r[q] + bm;
        }
    }
}

template<int SY, int SZ, int LOUT, int MODE, int NI>
__device__ __forceinline__ void pw_pass(const float* __restrict__ Yb, int i0,
                                        const float* __restrict__ Wh,
                                        const float* __restrict__ bias,
                                        float* __restrict__ Zb, int tid)
{
    constexpr int CH = (LOUT + 7) / 8;
    for (int u = tid; u < Cc * CH; u += 512) {
        int o  = u % Cc;
        int p0 = (u / Cc) * 8;
        const float* wp = Wh + o;
        float a0=0.f,a1=0.f,a2=0.f,a3=0.f,a4=0.f,a5=0.f,a6=0.f,a7=0.f;
        for (int i = 0; i < NI; ++i) {
            float w = wp[i * Cc];
            const float4* y4 = reinterpret_cast<const float4*>(Yb + (i0 + i) * SY + p0);
            float4 ya = y4[0], yb = y4[1];
            a0 += w*ya.x; a1 += w*ya.y; a2 += w*ya.z; a3 += w*ya.w;
            a4 += w*yb.x; a5 += w*yb.y; a6 += w*yb.z; a7 += w*yb.w;
        }
        float* dst = Zb + o * SZ + p0;
        float r[8] = {a0,a1,a2,a3,a4,a5,a6,a7};
        if constexpr (MODE == 0) {
#pragma unroll
            for (int q = 0; q < 8; ++q) if (p0 + q < LOUT) dst[q] = r[q];
        } else {
            float bm = bias[o];
#pragma unroll
            for (int q = 0; q < 8; ++q) if (p0 + q < LOUT) dst[q] = dst[q] + r[q] + bm;
        }
    }
}

__device__ __forceinline__ void load_w_kx(const float* __restrict__ src, int KS, int koff, int nk,
                                          float* __restrict__ W, int tid)
{   // W[k*62+m] = src[m*KS + koff + k]
    for (int n = tid; n < nk*Cc; n += 512) {
        int k = n / Cc, m = n - k*Cc;
        W[n] = src[m*KS + koff + k];
    }
}

__device__ __forceinline__ void load_w_pw(const float* __restrict__ src, int ioff,
                                          float* __restrict__ W, int tid)
{   // W[ii*62+o] = src[o*62 + ioff + ii], ii<31
    for (int n = tid; n < 31*Cc; n += 512) {
        int ii = n / Cc, o = n - ii*Cc;
        W[n] = src[o*Cc + ioff + ii];
    }
}

__global__ __launch_bounds__(512, 4) void k_dsc(const float* __restrict__ x,
    const float* __restrict__ dwk1, const float* __restrict__ dwb1,
    const float* __restrict__ pwk1, const float* __restrict__ pwb1,
    const float* __restrict__ dwk2, const float* __restrict__ dwb2,
    const float* __restrict__ pwk2, const float* __restrict__ pwb2,
    const float* __restrict__ dwk3, const float* __restrict__ dwb3,
    const float* __restrict__ pwk3, const float* __restrict__ pwb3,
    float* __restrict__ d61)
{
    __shared__ __align__(16) float X[10488];
    __shared__ __align__(16) float A[6704];
    __shared__ __align__(16) float W[1984];
    const int tid = threadIdx.x;
    const int bt = blockIdx.x, t = bt >> 6, b = bt & 63;
    const float* xrow = x + (size_t)(b*Ss + t) * CL;

    for (int i = tid; i < CL; i += 512) X[i] = xrow[i];
    load_w_kx(dwk1, 64, 0, 32, W, tid);
    __syncthreads();
    dw_pass<32,169,108,106,0>(X, 0, W, nullptr, A, tid);       // y1 partial (k 0..31)
    __syncthreads();
    load_w_kx(dwk1, 64, 32, 32, W, tid);
    __syncthreads();
    dw_pass<32,169,108,106,1>(X, 32, W, dwb1, A, tid);         // y1 += (k 32..63) + bias
    __syncthreads();
    load_w_pw(pwk1, 0, W, tid);
    __syncthreads();
    pw_pass<108,109,106,0,31>(A, 0, W, nullptr, X, tid);       // z1 partial (i 0..30)
    __syncthreads();
    load_w_pw(pwk1, 31, W, tid);
    __syncthreads();
    pw_pass<108,109,106,1,31>(A, 31, W, pwb1, X, tid);         // z1 += (i 31..61) + bias
    __syncthreads();
    load_w_kx(dwk2, 32, 0, 32, W, tid);
    __syncthreads();
    dw_pass<32,109,84,75,2>(X, 0, W, dwb2, A, tid);            // y2
    __syncthreads();
    load_w_pw(pwk2, 0, W, tid);
    __syncthreads();
    pw_pass<84,81,75,0,31>(A, 0, W, nullptr, X, tid);          // z2 partial
    __syncthreads();
    load_w_pw(pwk2, 31, W, tid);
    __syncthreads();
    pw_pass<84,81,75,1,31>(A, 31, W, pwb2, X, tid);            // z2 done
    __syncthreads();
    load_w_kx(dwk3, 14, 0, 14, W, tid);
    __syncthreads();
    dw_pass<14,81,68,62,2>(X, 0, W, dwb3, A, tid);             // y3
    __syncthreads();
    if (tid < Cc) {                                            // pw3: only row 61 needed
        float acc = pwb3[61];
        for (int i = 0; i < Cc; ++i) acc += pwk3[61*Cc + i] * A[i*68 + tid];
        d61[(size_t)bt*Cc + tid] = acc;
    }
}

// ---------------- K7: adj_t row, v, g, pre-gates per (b,t) ----------------
__global__ __launch_bounds__(256) void k_g(const float* __restrict__ x, const float* __restrict__ d61,
    const float* __restrict__ adjr, const float* __restrict__ gcn_w, const float* __restrict__ gcn_b,
    const float* __restrict__ w_r, const float* __restrict__ w_u, const float* __restrict__ w_c,
    float* __restrict__ preR, float* __restrict__ preU, float* __restrict__ preC)
{
    __shared__ float adjt[Cc];
    __shared__ float v[Ll];
    __shared__ float g[GRU];
    int bt = blockIdx.x, t = bt >> 6, b = bt & 63;
    int tid = threadIdx.x;
    if (tid < Cc) {
        float sv = d61[(size_t)bt*Cc + tid] + adjr[b*Cc + tid];
        adjt[tid] = 1.f / (1.f + expf(-sv));
    }
    __syncthreads();
    if (tid < Ll) {
        const float* xp = x + (size_t)(b*Ss + t)*CL + tid;
        float acc = 0.f;
        for (int j = 0; j < Cc; ++j) acc += adjt[j] * xp[j*Ll];
        v[tid] = acc;
    }
    __syncthreads();
    if (tid < GRU) {
        float acc = gcn_b[tid];
        for (int l = 0; l < Ll; ++l) acc += v[l] * gcn_w[l*GRU + tid];
        g[tid] = acc;
    }
    __syncthreads();
    if (tid < GRU) {
        float ar = 0.f, au = 0.f, ac = 0.f;
        for (int i = 0; i < GRU; ++i) {
            float gi = g[i];
            ar += gi * w_r[i*GRU + tid];
            au += gi * w_u[i*GRU + tid];
            ac += gi * w_c[i*GRU + tid];
        }
        preR[(size_t)bt*GRU + tid] = ar;
        preU[(size_t)bt*GRU + tid] = au;
        preC[(size_t)bt*GRU + tid] = ac;
    }
}

// ---------------- K8: GRU scan over t ----------------
__global__ __launch_bounds__(64) void k_gru(const float* __restrict__ preR, const float* __restrict__ preU,
    const float* __restrict__ preC,
    const float* __restrict__ w_r, const float* __restrict__ wb_r,
    const float* __restrict__ w_u, const float* __restrict__ wb_u,
    const float* __restrict__ w_c, const float* __restrict__ wb_c,
    const float* __restrict__ b_r, const float* __restrict__ b_u, const float* __restrict__ b_c,
    float* __restrict__ out)
{
    __shared__ float W2r[GRU*GRU], W2u[GRU*GRU], W2c[GRU*GRU];
    __shared__ float h[GRU], rh[GRU];
    int b = blockIdx.x, o = threadIdx.x;
    for (int i = 0; i < GRU; ++i) {
        W2r[i*GRU + o] = w_r[(GRU + i)*GRU + o];
        W2u[i*GRU + o] = w_u[(GRU + i)*GRU + o];
        W2c[i*GRU + o] = w_c[(GRU + i)*GRU + o];
    }
    float cr = wb_r[o] + b_r[o];
    float cu = wb_u[o] + b_u[o];
    float cc = wb_c[o] + b_c[o];
    float hreg = 0.f;
    h[o] = 0.f;
    __syncthreads();
    for (int t = 0; t < Ss; ++t) {
        size_t base = (size_t)(t*Bb + b)*GRU + o;
        float ar = preR[base] + cr;
        float au = preU[base] + cu;
        for (int i = 0; i < GRU; ++i) {
            float hi = h[i];
            ar += hi * W2r[i*GRU + o];
            au += hi * W2u[i*GRU + o];
        }
        float r = 1.f / (1.f + expf(-ar));
        float u = 1.f / (1.f + expf(-au));
        rh[o] = r * hreg;
        __syncthreads();
        float ac = preC[base] + cc;
        for (int i = 0; i < GRU; ++i) ac += rh[i] * W2c[i*GRU + o];
        float ct = tanhf(ac);
        hreg = u * hreg + (1.f - u) * ct;
        __syncthreads();
        h[o] = hreg;
        __syncthreads();
    }
    out[b*GRU + o] = hreg;
}

// ---------------- launcher ----------------
extern "C" void kernel_launch(void* const* d_in, const int* in_sizes, int n_in,
                              void* d_out, int out_size, void* d_ws, size_t ws_size,
                              hipStream_t stream)
{
    const float* x     = (const float*)d_in[0];
    const float* se_w1 = (const float*)d_in[1];
    const float* se_w2 = (const float*)d_in[2];
    const float* dwk1  = (const float*)d_in[3];
    const float* dwb1  = (const float*)d_in[4];
    const float* pwk1  = (const float*)d_in[5];
    const float* pwb1  = (const float*)d_in[6];
    const float* dwk2  = (const float*)d_in[7];
    const float* dwb2  = (const float*)d_in[8];
    const float* pwk2  = (const float*)d_in[9];
    const float* pwb2  = (const float*)d_in[10];
    const float* dwk3  = (const float*)d_in[11];
    const float* dwb3  = (const float*)d_in[12];
    const float* pwk3  = (const float*)d_in[13];
    const float* pwb3  = (const float*)d_in[14];
    const float* gcn_w = (const float*)d_in[15];
    const float* gcn_b = (const float*)d_in[16];
    const float* w_r   = (const float*)d_in[17];
    const float* wb_r  = (const float*)d_in[18];
    const float* w_u   = (const float*)d_in[19];
    const float* wb_u  = (const float*)d_in[20];
    const float* w_c   = (const float*)d_in[21];
    const float* wb_c  = (const float*)d_in[22];
    const float* b_r   = (const float*)d_in[23];
    const float* b_u   = (const float*)d_in[24];
    const float* b_c   = (const float*)d_in[25];
    float* out = (float*)d_out;

    float* ws = (float*)d_ws;
    float* sq   = ws;                    // 1920
    float* aw   = sq   + 1920;           // 1920
    float* msb  = aw   + 1920;           // 670592
    float* fre  = msb  + 670592;         // 670592
    float* fim  = fre  + 670592;         // 670592
    float* adjr = fim  + 670592;         // 3968
    float* d61  = adjr + 3968;           // 119040
    float* preR = d61  + 119040;         // 122880
    float* preU = preR + 122880;         // 122880
    float* preC = preU + 122880;         // 122880

    k_sq<<<Bb*Ss, 256, 0, stream>>>(x, sq);
    k_se<<<1, 64, 0, stream>>>(sq, se_w1, se_w2, aw);
    k_maxseg<<<(Bb*CL + 255)/256, 256, 0, stream>>>(x, aw, msb);
    k_dft<<<Bb*Cc, 256, 0, stream>>>(msb, fre, fim);
    k_adjrow<<<Bb*Cc, 64, 0, stream>>>(fre, fim, adjr);
    k_dsc<<<Ss*Bb, 512, 0, stream>>>(x, dwk1, dwb1, pwk1, pwb1, dwk2, dwb2, pwk2, pwb2,
                                     dwk3, dwb3, pwk3, pwb3, d61);
    k_g<<<Ss*Bb, 256, 0, stream>>>(x, d61, adjr, gcn_w, gcn_b, w_r, w_u, w_c, preR, preU, preC);
    k_gru<<<Bb, 64, 0, stream>>>(preR, preU, preC, w_r, wb_r, w_u, wb_u, w_c, wb_c,
                                 b_r, b_u, b_c, out);
}

// Round 4
// 486.702 us; speedup vs baseline: 4.4239x; 4.4239x over previous
//
#include <hip/hip_runtime.h>
#include <hip/hip_bf16.h>
#include <math.h>

#define Bb 64
#define Ss 30
#define Cc 62
#define Ll 169
#define CL (Cc*Ll)          // 10478
#define GRU 64
#define HTAPS 108           // 64+32+14-2
#define MT 64               // GEMM M tile
#define KSPLIT 8
#define KSLICE 1312         // 8*1312 >= 10478, even
#define SUBK 64
#define XS_STRIDE 68        // mult of 4 for float4 reads

// ---------------- K1: sq[b,s] = mean over (c,L) ----------------
__global__ __launch_bounds__(256) void k_sq(const float* __restrict__ x, float* __restrict__ sq)
{
    __shared__ float red[4];
    int bs = blockIdx.x;
    const float* p = x + (size_t)bs * CL;
    float acc = 0.f;
    for (int i = threadIdx.x; i < CL; i += 256) acc += p[i];
    for (int off = 32; off; off >>= 1) acc += __shfl_down(acc, off);
    if ((threadIdx.x & 63) == 0) red[threadIdx.x >> 6] = acc;
    __syncthreads();
    if (threadIdx.x == 0) sq[bs] = (red[0] + red[1] + red[2] + red[3]) / (float)CL;
}

// ---------------- K2: SE MLP -> a[b,s] ----------------
__global__ __launch_bounds__(64) void k_se(const float* __restrict__ sq, const float* __restrict__ w1,
                                           const float* __restrict__ w2, float* __restrict__ aout)
{
    int b = threadIdx.x;
    float hid[15];
#pragma unroll
    for (int j = 0; j < 15; ++j) {
        float h = 0.f;
        for (int s = 0; s < Ss; ++s) h += sq[b*Ss + s] * w1[s*15 + j];
        hid[j] = fmaxf(h, 0.f);
    }
    for (int s = 0; s < Ss; ++s) {
        float o = 0.f;
#pragma unroll
        for (int j = 0; j < 15; ++j) o += hid[j] * w2[j*Ss + s];
        aout[b*Ss + s] = 1.f / (1.f + expf(-o));
    }
}

// ---------------- K3: max_seg[b,c,l] = max_s a[b,s]*x[b,s,c,l] ----------------
__global__ __launch_bounds__(256) void k_maxseg(const float* __restrict__ x, const float* __restrict__ a,
                                                float* __restrict__ ms)
{
    int idx = blockIdx.x * 256 + threadIdx.x;
    if (idx >= Bb*CL) return;
    int b = idx / CL;
    int rem = idx - b*CL;
    float m = -INFINITY;
    for (int s = 0; s < Ss; ++s) {
        float v = x[(size_t)(b*Ss + s)*CL + rem] * a[b*Ss + s];
        m = fmaxf(m, v);
    }
    ms[idx] = m;
}

// ---------------- K4: direct DFT per (b,c) row ----------------
__global__ __launch_bounds__(256) void k_dft(const float* __restrict__ ms, float* __restrict__ fre,
                                             float* __restrict__ fim)
{
    __shared__ float xr[Ll], ct[Ll], st[Ll];
    int row = blockIdx.x;
    int tid = threadIdx.x;
    if (tid < Ll) {
        xr[tid] = ms[(size_t)row*Ll + tid];
        float ang = (float)tid * (6.28318530717958647692f / (float)Ll);
        ct[tid] = cosf(ang);
        st[tid] = sinf(ang);
    }
    __syncthreads();
    if (tid < Ll) {
        int k = tid;
        float re = 0.f, im = 0.f;
        int idx = 0;
        for (int n = 0; n < Ll; ++n) {
            float v = xr[n];
            re += v * ct[idx];
            im -= v * st[idx];
            idx += k; if (idx >= Ll) idx -= Ll;
        }
        fre[(size_t)row*Ll + k] = re;
        fim[(size_t)row*Ll + k] = im;
    }
}

// ---------------- K5: adj row 61 ----------------
__global__ __launch_bounds__(64) void k_adjrow(const float* __restrict__ fre, const float* __restrict__ fim,
                                               float* __restrict__ adjr)
{
    int b = blockIdx.x / Cc;
    int j = blockIdx.x % Cc;
    int lane = threadIdx.x;
    const float* re61 = fre + (size_t)(b*Cc + 61)*Ll;
    const float* im61 = fim + (size_t)(b*Cc + 61)*Ll;
    const float* rej  = fre + (size_t)(b*Cc + j)*Ll;
    const float* imj  = fim + (size_t)(b*Cc + j)*Ll;
    float num = 0.f, den = 0.f;
    for (int l = lane; l < Ll; l += 64) {
        float ar = re61[l], ai = im61[l];
        float br = rej[l],  bi = imj[l];
        num += ai*br - ar*bi;
        den += sqrtf(ar*ar + ai*ai) * sqrtf(br*br + bi*bi);
    }
    for (int off = 32; off; off >>= 1) { num += __shfl_down(num, off); den += __shfl_down(den, off); }
    if (lane == 0) adjr[b*Cc + j] = (j == 61) ? 0.f : num / den;
}

// ---------------- K6a: compose effective filter Heff[62][108] + scalar C ----------------
// d61[j] = C + sum_{c,a} Heff[c][a] * x[c][j+a]
__global__ __launch_bounds__(256) void k_heff(
    const float* __restrict__ dwk1, const float* __restrict__ dwb1,
    const float* __restrict__ pwk1, const float* __restrict__ pwb1,
    const float* __restrict__ dwk2, const float* __restrict__ dwb2,
    const float* __restrict__ pwk2, const float* __restrict__ pwb2,
    const float* __restrict__ dwk3, const float* __restrict__ dwb3,
    const float* __restrict__ pwk3, const float* __restrict__ pwb3,
    float* __restrict__ HeffG, float* __restrict__ CconstG)
{
    __shared__ float F[Cc*14];    // F[e][t] = sum_f P3row[f]*P2[f,e]*k3[f,t]
    __shared__ float G[Cc*45];    // G[e] = F[e] conv k2[e]   (poly mult, len 45)
    __shared__ float H1[Cc*45];   // H1[c][s] = sum_e P1[e,c]*G[e][s]
    __shared__ float cA[Cc], cB[Cc];
    int tid = threadIdx.x;

    for (int u = tid; u < Cc*14; u += 256) {
        int e = u / 14, t = u % 14;
        float acc = 0.f;
        for (int f = 0; f < Cc; ++f)
            acc += pwk3[61*Cc + f] * pwk2[f*Cc + e] * dwk3[f*14 + t];
        F[u] = acc;
    }
    __syncthreads();
    for (int u = tid; u < Cc*45; u += 256) {
        int e = u / 45, s = u % 45;
        float acc = 0.f;
        int t0 = s - 31; if (t0 < 0) t0 = 0;
        int t1 = s; if (t1 > 13) t1 = 13;
        for (int t = t0; t <= t1; ++t)
            acc += F[e*14 + t] * dwk2[e*32 + (s - t)];
        G[u] = acc;
    }
    __syncthreads();
    for (int u = tid; u < Cc*45; u += 256) {
        int c = u / 45, s = u % 45;
        float acc = 0.f;
        for (int e = 0; e < Cc; ++e)
            acc += pwk1[e*Cc + c] * G[e*45 + s];
        H1[u] = acc;
    }
    __syncthreads();
    for (int u = tid; u < Cc*HTAPS; u += 256) {
        int c = u / HTAPS, a = u % HTAPS;
        float acc = 0.f;
        int s0 = a - 63; if (s0 < 0) s0 = 0;
        int s1 = a; if (s1 > 44) s1 = 44;
        for (int s = s0; s <= s1; ++s)
            acc += H1[c*45 + s] * dwk1[c*64 + (a - s)];
        HeffG[u] = acc;
    }
    // bias constant
    if (tid < Cc) {
        int e = tid;
        float acc = pwb1[e];
        for (int c = 0; c < Cc; ++c) acc += pwk1[e*Cc + c] * dwb1[c];
        float sk = 0.f;
        for (int a = 0; a < 32; ++a) sk += dwk2[e*32 + a];
        cA[e] = acc * sk + dwb2[e];
    }
    __syncthreads();
    if (tid < Cc) {
        int f = tid;
        float acc = pwb2[f];
        for (int e = 0; e < Cc; ++e) acc += pwk2[f*Cc + e] * cA[e];
        float sk = 0.f;
        for (int t = 0; t < 14; ++t) sk += dwk3[f*14 + t];
        cB[f] = acc * sk + dwb3[f];
    }
    __syncthreads();
    if (tid == 0) {
        float acc = pwb3[61];
        for (int f = 0; f < Cc; ++f) acc += pwk3[61*Cc + f] * cB[f];
        CconstG[0] = acc;
    }
}

// ---------------- K6b: build Hbig[10478][62] ----------------
__global__ __launch_bounds__(256) void k_hbig(const float* __restrict__ Heff, float* __restrict__ Hbig)
{
    int idx = blockIdx.x * 256 + threadIdx.x;
    if (idx >= CL * Cc) return;
    int row = idx / Cc, j = idx - row * Cc;     // row = c*169 + l
    int c = row / Ll, l = row - c * Ll;
    int a = l - j;
    Hbig[idx] = (a >= 0 && a < HTAPS) ? Heff[c*HTAPS + a] : 0.f;
}

// ---------------- K6c: GEMM  P[ks][1920][62] partial = X[.,kslice] * Hbig[kslice,.] ----------------
__global__ __launch_bounds__(256) void k_gemm(const float* __restrict__ x,
                                              const float* __restrict__ Hbig,
                                              float* __restrict__ P)
{
    __shared__ __align__(16) float Xs[MT * XS_STRIDE];  // 64x64 (stride 68)
    __shared__ __align__(16) float Hs[SUBK * 64];       // 64x64 (cols 62 + zero pad)
    const int tid = threadIdx.x;
    const int mt = blockIdx.x % (1920 / MT);            // 30 M tiles
    const int ks = blockIdx.x / (1920 / MT);            // 8 K splits
    const int k0 = ks * KSLICE;
    const int kend = (k0 + KSLICE < CL) ? (k0 + KSLICE) : CL;
    const int m0g = mt * MT;
    const int n0 = (tid & 15) * 4;
    const int mg = tid >> 4;                            // 0..15

    float acc[4][4];
#pragma unroll
    for (int i = 0; i < 4; ++i) { acc[i][0]=0.f; acc[i][1]=0.f; acc[i][2]=0.f; acc[i][3]=0.f; }

    for (int kb = k0; kb < kend; kb += SUBK) {
        // stage X tile: 64 rows x 64 cols as float2
        for (int u = tid; u < MT*32; u += 256) {
            int r = u >> 5, c2 = u & 31;
            int col = kb + 2*c2;
            float2 v = make_float2(0.f, 0.f);
            if (col < kend) v = *reinterpret_cast<const float2*>(x + (size_t)(m0g + r)*CL + col);
            Xs[r*XS_STRIDE + 2*c2]     = v.x;
            Xs[r*XS_STRIDE + 2*c2 + 1] = v.y;
        }
        // stage H tile: 64 rows x 62 cols (+pad)
        for (int u = tid; u < SUBK*64; u += 256) {
            int r = u >> 6, j = u & 63;
            int kg = kb + r;
            Hs[u] = (j < Cc && kg < kend) ? Hbig[(size_t)kg*Cc + j] : 0.f;
        }
        __syncthreads();
        for (int kk = 0; kk < SUBK; kk += 4) {
            const float4 hv0 = *reinterpret_cast<const float4*>(&Hs[(kk+0)*64 + n0]);
            const float4 hv1 = *reinterpret_cast<const float4*>(&Hs[(kk+1)*64 + n0]);
            const float4 hv2 = *reinterpret_cast<const float4*>(&Hs[(kk+2)*64 + n0]);
            const float4 hv3 = *reinterpret_cast<const float4*>(&Hs[(kk+3)*64 + n0]);
#pragma unroll
            for (int i = 0; i < 4; ++i) {
                const float4 xv = *reinterpret_cast<const float4*>(&Xs[(mg + 16*i)*XS_STRIDE + kk]);
                acc[i][0] += xv.x*hv0.x + xv.y*hv1.x + xv.z*hv2.x + xv.w*hv3.x;
                acc[i][1] += xv.x*hv0.y + xv.y*hv1.y + xv.z*hv2.y + xv.w*hv3.y;
                acc[i][2] += xv.x*hv0.z + xv.y*hv1.z + xv.z*hv2.z + xv.w*hv3.z;
                acc[i][3] += xv.x*hv0.w + xv.y*hv1.w + xv.z*hv2.w + xv.w*hv3.w;
            }
        }
        __syncthreads();
    }
#pragma unroll
    for (int i = 0; i < 4; ++i) {
        int row = m0g + mg + 16*i;
        float* dst = P + (size_t)(ks*1920 + row)*Cc + n0;
#pragma unroll
        for (int q = 0; q < 4; ++q)
            if (n0 + q < Cc) dst[q] = acc[i][q];
    }
}

// ---------------- K6d: reduce partials -> d61[m][j] (m = b*30+t) ----------------
__global__ __launch_bounds__(256) void k_dred(const float* __restrict__ P,
                                              const float* __restrict__ Cconst,
                                              float* __restrict__ d61)
{
    int idx = blockIdx.x * 256 + threadIdx.x;
    if (idx >= 1920 * Cc) return;
    float a = Cconst[0];
#pragma unroll
    for (int ks = 0; ks < KSPLIT; ++ks) a += P[(size_t)ks * (1920*Cc) + idx];
    d61[idx] = a;
}

// ---------------- K7: adj_t row, v, g, pre-gates per (b,t) ----------------
__global__ __launch_bounds__(256) void k_g(const float* __restrict__ x, const float* __restrict__ d61,
    const float* __restrict__ adjr, const float* __restrict__ gcn_w, const float* __restrict__ gcn_b,
    const float* __restrict__ w_r, const float* __restrict__ w_u, const float* __restrict__ w_c,
    float* __restrict__ preR, float* __restrict__ preU, float* __restrict__ preC)
{
    __shared__ float adjt[Cc];
    __shared__ float v[Ll];
    __shared__ float g[GRU];
    int bt = blockIdx.x, t = bt >> 6, b = bt & 63;
    int m = b * Ss + t;
    int tid = threadIdx.x;
    if (tid < Cc) {
        float sv = d61[(size_t)m*Cc + tid] + adjr[b*Cc + tid];
        adjt[tid] = 1.f / (1.f + expf(-sv));
    }
    __syncthreads();
    if (tid < Ll) {
        const float* xp = x + (size_t)m*CL + tid;
        float acc = 0.f;
        for (int j = 0; j < Cc; ++j) acc += adjt[j] * xp[j*Ll];
        v[tid] = acc;
    }
    __syncthreads();
    if (tid < GRU) {
        float acc = gcn_b[tid];
        for (int l = 0; l < Ll; ++l) acc += v[l] * gcn_w[l*GRU + tid];
        g[tid] = acc;
    }
    __syncthreads();
    if (tid < GRU) {
        float ar = 0.f, au = 0.f, ac = 0.f;
        for (int i = 0; i < GRU; ++i) {
            float gi = g[i];
            ar += gi * w_r[i*GRU + tid];
            au += gi * w_u[i*GRU + tid];
            ac += gi * w_c[i*GRU + tid];
        }
        preR[(size_t)bt*GRU + tid] = ar;
        preU[(size_t)bt*GRU + tid] = au;
        preC[(size_t)bt*GRU + tid] = ac;
    }
}

// ---------------- K8: GRU scan over t ----------------
__global__ __launch_bounds__(64) void k_gru(const float* __restrict__ preR, const float* __restrict__ preU,
    const float* __restrict__ preC,
    const float* __restrict__ w_r, const float* __restrict__ wb_r,
    const float* __restrict__ w_u, const float* __restrict__ wb_u,
    const float* __restrict__ w_c, const float* __restrict__ wb_c,
    const float* __restrict__ b_r, const float* __restrict__ b_u, const float* __restrict__ b_c,
    float* __restrict__ out)
{
    __shared__ float W2r[GRU*GRU], W2u[GRU*GRU], W2c[GRU*GRU];
    __shared__ float h[GRU], rh[GRU];
    int b = blockIdx.x, o = threadIdx.x;
    for (int i = 0; i < GRU; ++i) {
        W2r[i*GRU + o] = w_r[(GRU + i)*GRU + o];
        W2u[i*GRU + o] = w_u[(GRU + i)*GRU + o];
        W2c[i*GRU + o] = w_c[(GRU + i)*GRU + o];
    }
    float cr = wb_r[o] + b_r[o];
    float cu = wb_u[o] + b_u[o];
    float cc = wb_c[o] + b_c[o];
    float hreg = 0.f;
    h[o] = 0.f;
    __syncthreads();
    for (int t = 0; t < Ss; ++t) {
        size_t base = (size_t)(t*Bb + b)*GRU + o;
        float ar = preR[base] + cr;
        float au = preU[base] + cu;
        for (int i = 0; i < GRU; ++i) {
            float hi = h[i];
            ar += hi * W2r[i*GRU + o];
            au += hi * W2u[i*GRU + o];
        }
        float r = 1.f / (1.f + expf(-ar));
        float u = 1.f / (1.f + expf(-au));
        rh[o] = r * hreg;
        __syncthreads();
        float ac = preC[base] + cc;
        for (int i = 0; i < GRU; ++i) ac += rh[i] * W2c[i*GRU + o];
        float ct = tanhf(ac);
        hreg = u * hreg + (1.f - u) * ct;
        __syncthreads();
        h[o] = hreg;
        __syncthreads();
    }
    out[b*GRU + o] = hreg;
}

// ---------------- launcher ----------------
extern "C" void kernel_launch(void* const* d_in, const int* in_sizes, int n_in,
                              void* d_out, int out_size, void* d_ws, size_t ws_size,
                              hipStream_t stream)
{
    const float* x     = (const float*)d_in[0];
    const float* se_w1 = (const float*)d_in[1];
    const float* se_w2 = (const float*)d_in[2];
    const float* dwk1  = (const float*)d_in[3];
    const float* dwb1  = (const float*)d_in[4];
    const float* pwk1  = (const float*)d_in[5];
    const float* pwb1  = (const float*)d_in[6];
    const float* dwk2  = (const float*)d_in[7];
    const float* dwb2  = (const float*)d_in[8];
    const float* pwk2  = (const float*)d_in[9];
    const float* pwb2  = (const float*)d_in[10];
    const float* dwk3  = (const float*)d_in[11];
    const float* dwb3  = (const float*)d_in[12];
    const float* pwk3  = (const float*)d_in[13];
    const float* pwb3  = (const float*)d_in[14];
    const float* gcn_w = (const float*)d_in[15];
    const float* gcn_b = (const float*)d_in[16];
    const float* w_r   = (const float*)d_in[17];
    const float* wb_r  = (const float*)d_in[18];
    const float* w_u   = (const float*)d_in[19];
    const float* wb_u  = (const float*)d_in[20];
    const float* w_c   = (const float*)d_in[21];
    const float* wb_c  = (const float*)d_in[22];
    const float* b_r   = (const float*)d_in[23];
    const float* b_u   = (const float*)d_in[24];
    const float* b_c   = (const float*)d_in[25];
    float* out = (float*)d_out;

    // workspace layout (floats). msb/f_re/f_im region (3x670592) is dead after
    // k_adjrow and is reused for P (8*119040=952320) and Hbig (649636):
    // both fit in 2011776 with room to spare.
    float* ws   = (float*)d_ws;
    float* sq   = ws;                    // 1920
    float* aw   = sq   + 1920;           // 1920
    float* msb  = aw   + 1920;           // 670592
    float* f_re = msb  + 670592;         // 670592
    float* f_im = f_re + 670592;         // 670592
    float* adjr = f_im + 670592;         // 3968
    float* d61  = adjr + 3968;           // 119040
    float* preR = d61  + 119040;         // 122880
    float* preU = preR + 122880;         // 122880
    float* preC = preU + 122880;         // 122880
    float* Heff = preC + 122880;         // 6696
    float* Ccst = Heff + 6696;           // 8
    float* P    = msb;                   // alias (952320)
    float* Hbig = msb + 952320;          // alias (649636), disjoint from P

    k_sq<<<Bb*Ss, 256, 0, stream>>>(x, sq);
    k_se<<<1, 64, 0, stream>>>(sq, se_w1, se_w2, aw);
    k_maxseg<<<(Bb*CL + 255)/256, 256, 0, stream>>>(x, aw, msb);
    k_dft<<<Bb*Cc, 256, 0, stream>>>(msb, f_re, f_im);
    k_adjrow<<<Bb*Cc, 64, 0, stream>>>(f_re, f_im, adjr);
    k_heff<<<1, 256, 0, stream>>>(dwk1, dwb1, pwk1, pwb1, dwk2, dwb2, pwk2, pwb2,
                                  dwk3, dwb3, pwk3, pwb3, Heff, Ccst);
    k_hbig<<<(CL*Cc + 255)/256, 256, 0, stream>>>(Heff, Hbig);
    k_gemm<<<(1920/MT)*KSPLIT, 256, 0, stream>>>(x, Hbig, P);
    k_dred<<<(1920*Cc + 255)/256, 256, 0, stream>>>(P, Ccst, d61);
    k_g<<<Ss*Bb, 256, 0, stream>>>(x, d61, adjr, gcn_w, gcn_b, w_r, w_u, w_c, preR, preU, preC);
    k_gru<<<Bb, 64, 0, stream>>>(preR, preU, preC, w_r, wb_r, w_u, wb_u, w_c, wb_c,
                                 b_r, b_u, b_c, out);
}

// Round 5
// 423.200 us; speedup vs baseline: 5.0878x; 1.1501x over previous
//
#include <hip/hip_runtime.h>
#include <hip/hip_bf16.h>
#include <math.h>

#define Bb 64
#define Ss 30
#define Cc 62
#define Ll 169
#define CL (Cc*Ll)          // 10478
#define GRU 64
#define HTAPS 108           // 64+32+14-2
#define MT 32               // GEMM M tile
#define KSPLIT 16
#define KSLICE 656          // 16*656 >= 10478
#define SUBK 64
#define XS_STRIDE 68        // mult of 4 for float4 reads

// ---------------- K1: sq[b,s] = mean over (c,L) ----------------
__global__ __launch_bounds__(256) void k_sq(const float* __restrict__ x, float* __restrict__ sq)
{
    __shared__ float red[4];
    int bs = blockIdx.x;
    const float* p = x + (size_t)bs * CL;
    float acc = 0.f;
    for (int i = threadIdx.x; i < CL; i += 256) acc += p[i];
    for (int off = 32; off; off >>= 1) acc += __shfl_down(acc, off);
    if ((threadIdx.x & 63) == 0) red[threadIdx.x >> 6] = acc;
    __syncthreads();
    if (threadIdx.x == 0) sq[bs] = (red[0] + red[1] + red[2] + red[3]) / (float)CL;
}

// ---------------- K2: SE MLP -> a[b,s] ----------------
__global__ __launch_bounds__(64) void k_se(const float* __restrict__ sq, const float* __restrict__ w1,
                                           const float* __restrict__ w2, float* __restrict__ aout)
{
    int b = threadIdx.x;
    float hid[15];
#pragma unroll
    for (int j = 0; j < 15; ++j) {
        float h = 0.f;
        for (int s = 0; s < Ss; ++s) h += sq[b*Ss + s] * w1[s*15 + j];
        hid[j] = fmaxf(h, 0.f);
    }
    for (int s = 0; s < Ss; ++s) {
        float o = 0.f;
#pragma unroll
        for (int j = 0; j < 15; ++j) o += hid[j] * w2[j*Ss + s];
        aout[b*Ss + s] = 1.f / (1.f + expf(-o));
    }
}

// ---------------- K3: max_seg[b,c,l] = max_s a[b,s]*x[b,s,c,l] ----------------
__global__ __launch_bounds__(256) void k_maxseg(const float* __restrict__ x, const float* __restrict__ a,
                                                float* __restrict__ ms)
{
    int idx = blockIdx.x * 256 + threadIdx.x;
    if (idx >= Bb*CL) return;
    int b = idx / CL;
    int rem = idx - b*CL;
    float m = -INFINITY;
    for (int s = 0; s < Ss; ++s) {
        float v = x[(size_t)(b*Ss + s)*CL + rem] * a[b*Ss + s];
        m = fmaxf(m, v);
    }
    ms[idx] = m;
}

// ---------------- K4: direct DFT per (b,c) row ----------------
__global__ __launch_bounds__(192) void k_dft(const float* __restrict__ ms, float* __restrict__ fre,
                                             float* __restrict__ fim)
{
    __shared__ float xr[Ll], ct[Ll], st[Ll];
    int row = blockIdx.x;
    int tid = threadIdx.x;
    if (tid < Ll) {
        xr[tid] = ms[(size_t)row*Ll + tid];
        float ang = (float)tid * (6.28318530717958647692f / (float)Ll);
        ct[tid] = cosf(ang);
        st[tid] = sinf(ang);
    }
    __syncthreads();
    if (tid < Ll) {
        int k = tid;
        float re = 0.f, im = 0.f;
        int idx = 0;
        for (int n = 0; n < Ll; ++n) {
            float v = xr[n];
            re += v * ct[idx];
            im -= v * st[idx];
            idx += k; if (idx >= Ll) idx -= Ll;
        }
        fre[(size_t)row*Ll + k] = re;
        fim[(size_t)row*Ll + k] = im;
    }
}

// ---------------- K5: adj row 61 ----------------
__global__ __launch_bounds__(64) void k_adjrow(const float* __restrict__ fre, const float* __restrict__ fim,
                                               float* __restrict__ adjr)
{
    int b = blockIdx.x / Cc;
    int j = blockIdx.x % Cc;
    int lane = threadIdx.x;
    const float* re61 = fre + (size_t)(b*Cc + 61)*Ll;
    const float* im61 = fim + (size_t)(b*Cc + 61)*Ll;
    const float* rej  = fre + (size_t)(b*Cc + j)*Ll;
    const float* imj  = fim + (size_t)(b*Cc + j)*Ll;
    float num = 0.f, den = 0.f;
    for (int l = lane; l < Ll; l += 64) {
        float ar = re61[l], ai = im61[l];
        float br = rej[l],  bi = imj[l];
        num += ai*br - ar*bi;
        den += sqrtf(ar*ar + ai*ai) * sqrtf(br*br + bi*bi);
    }
    for (int off = 32; off; off >>= 1) { num += __shfl_down(num, off); den += __shfl_down(den, off); }
    if (lane == 0) adjr[b*Cc + j] = (j == 61) ? 0.f : num / den;
}

// ---------------- K6a: compose effective filter Heff[62][108] + scalar C ----------------
__global__ __launch_bounds__(256) void k_heff(
    const float* __restrict__ dwk1, const float* __restrict__ dwb1,
    const float* __restrict__ pwk1, const float* __restrict__ pwb1,
    const float* __restrict__ dwk2, const float* __restrict__ dwb2,
    const float* __restrict__ pwk2, const float* __restrict__ pwb2,
    const float* __restrict__ dwk3, const float* __restrict__ dwb3,
    const float* __restrict__ pwk3, const float* __restrict__ pwb3,
    float* __restrict__ HeffG, float* __restrict__ CconstG)
{
    __shared__ float F[Cc*14];    // F[e][t] = sum_f P3row[f]*P2[f,e]*k3[f,t]
    __shared__ float G[Cc*45];    // G[e] = F[e] conv k2[e]
    __shared__ float H1[Cc*45];   // H1[c][s] = sum_e P1[e,c]*G[e][s]
    __shared__ float cA[Cc], cB[Cc];
    int tid = threadIdx.x;

    for (int u = tid; u < Cc*14; u += 256) {
        int e = u / 14, t = u % 14;
        float acc = 0.f;
        for (int f = 0; f < Cc; ++f)
            acc += pwk3[61*Cc + f] * pwk2[f*Cc + e] * dwk3[f*14 + t];
        F[u] = acc;
    }
    __syncthreads();
    for (int u = tid; u < Cc*45; u += 256) {
        int e = u / 45, s = u % 45;
        float acc = 0.f;
        int t0 = s - 31; if (t0 < 0) t0 = 0;
        int t1 = s; if (t1 > 13) t1 = 13;
        for (int t = t0; t <= t1; ++t)
            acc += F[e*14 + t] * dwk2[e*32 + (s - t)];
        G[u] = acc;
    }
    __syncthreads();
    for (int u = tid; u < Cc*45; u += 256) {
        int c = u / 45, s = u % 45;
        float acc = 0.f;
        for (int e = 0; e < Cc; ++e)
            acc += pwk1[e*Cc + c] * G[e*45 + s];
        H1[u] = acc;
    }
    __syncthreads();
    for (int u = tid; u < Cc*HTAPS; u += 256) {
        int c = u / HTAPS, a = u % HTAPS;
        float acc = 0.f;
        int s0 = a - 63; if (s0 < 0) s0 = 0;
        int s1 = a; if (s1 > 44) s1 = 44;
        for (int s = s0; s <= s1; ++s)
            acc += H1[c*45 + s] * dwk1[c*64 + (a - s)];
        HeffG[u] = acc;
    }
    if (tid < Cc) {
        int e = tid;
        float acc = pwb1[e];
        for (int c = 0; c < Cc; ++c) acc += pwk1[e*Cc + c] * dwb1[c];
        float sk = 0.f;
        for (int a = 0; a < 32; ++a) sk += dwk2[e*32 + a];
        cA[e] = acc * sk + dwb2[e];
    }
    __syncthreads();
    if (tid < Cc) {
        int f = tid;
        float acc = pwb2[f];
        for (int e = 0; e < Cc; ++e) acc += pwk2[f*Cc + e] * cA[e];
        float sk = 0.f;
        for (int t = 0; t < 14; ++t) sk += dwk3[f*14 + t];
        cB[f] = acc * sk + dwb3[f];
    }
    __syncthreads();
    if (tid == 0) {
        float acc = pwb3[61];
        for (int f = 0; f < Cc; ++f) acc += pwk3[61*Cc + f] * cB[f];
        CconstG[0] = acc;
    }
}

// ---------------- K6c: GEMM  P[ks][1920][62] = X[.,kslice] * H(kslice,.) ----------------
// H row kg, col j = Heff[c][a] with c=kg/169, a=(kg%169)-j (0<=a<108), staged from global Heff.
__global__ __launch_bounds__(256) void k_gemm(const float* __restrict__ x,
                                              const float* __restrict__ Heff,
                                              float* __restrict__ P)
{
    __shared__ __align__(16) float Xs[MT * XS_STRIDE];  // 32x64 (stride 68)
    __shared__ __align__(16) float Hs[SUBK * 64];       // 64x64 (cols 62 + zero pad)
    const int tid = threadIdx.x;
    const int mt = blockIdx.x % (1920 / MT);            // 60 M tiles
    const int ks = blockIdx.x / (1920 / MT);            // 16 K splits
    const int k0 = ks * KSLICE;
    const int kend = (k0 + KSLICE < CL) ? (k0 + KSLICE) : CL;
    const int m0g = mt * MT;
    const int n0 = (tid & 15) * 4;
    const int mg = tid >> 4;                            // 0..15

    float acc[2][4];
#pragma unroll
    for (int i = 0; i < 2; ++i) { acc[i][0]=0.f; acc[i][1]=0.f; acc[i][2]=0.f; acc[i][3]=0.f; }

    for (int kb = k0; kb < kend; kb += SUBK) {
        // stage X tile: 32 rows x 64 cols as float2 (2 float2 per thread)
        for (int u = tid; u < MT*32; u += 256) {
            int r = u >> 5, c2 = u & 31;
            int col = kb + 2*c2;
            float2 v = make_float2(0.f, 0.f);
            if (col < kend) v = *reinterpret_cast<const float2*>(x + (size_t)(m0g + r)*CL + col);
            Xs[r*XS_STRIDE + 2*c2]     = v.x;
            Xs[r*XS_STRIDE + 2*c2 + 1] = v.y;
        }
        // stage H tile from Heff: 64 rows x 62 cols (+pad)
        for (int u = tid; u < SUBK*64; u += 256) {
            int r = u >> 6, j = u & 63;
            int kg = kb + r;
            float hv = 0.f;
            if (j < Cc && kg < kend) {
                int c = kg / Ll, l = kg - c * Ll;
                int a = l - j;
                if (a >= 0 && a < HTAPS) hv = Heff[c*HTAPS + a];
            }
            Hs[u] = hv;
        }
        __syncthreads();
        for (int kk = 0; kk < SUBK; kk += 4) {
            const float4 hv0 = *reinterpret_cast<const float4*>(&Hs[(kk+0)*64 + n0]);
            const float4 hv1 = *reinterpret_cast<const float4*>(&Hs[(kk+1)*64 + n0]);
            const float4 hv2 = *reinterpret_cast<const float4*>(&Hs[(kk+2)*64 + n0]);
            const float4 hv3 = *reinterpret_cast<const float4*>(&Hs[(kk+3)*64 + n0]);
#pragma unroll
            for (int i = 0; i < 2; ++i) {
                const float4 xv = *reinterpret_cast<const float4*>(&Xs[(mg + 16*i)*XS_STRIDE + kk]);
                acc[i][0] += xv.x*hv0.x + xv.y*hv1.x + xv.z*hv2.x + xv.w*hv3.x;
                acc[i][1] += xv.x*hv0.y + xv.y*hv1.y + xv.z*hv2.y + xv.w*hv3.y;
                acc[i][2] += xv.x*hv0.z + xv.y*hv1.z + xv.z*hv2.z + xv.w*hv3.z;
                acc[i][3] += xv.x*hv0.w + xv.y*hv1.w + xv.z*hv2.w + xv.w*hv3.w;
            }
        }
        __syncthreads();
    }
#pragma unroll
    for (int i = 0; i < 2; ++i) {
        int row = m0g + mg + 16*i;
        float* dst = P + (size_t)(ks*1920 + row)*Cc + n0;
#pragma unroll
        for (int q = 0; q < 4; ++q)
            if (n0 + q < Cc) dst[q] = acc[i][q];
    }
}

// ---------------- K6d: reduce partials -> d61[m][j] (m = b*30+t) ----------------
__global__ __launch_bounds__(256) void k_dred(const float* __restrict__ P,
                                              const float* __restrict__ Cconst,
                                              float* __restrict__ d61)
{
    int idx = blockIdx.x * 256 + threadIdx.x;
    if (idx >= 1920 * Cc) return;
    float a = Cconst[0];
#pragma unroll
    for (int ks = 0; ks < KSPLIT; ++ks) a += P[(size_t)ks * (1920*Cc) + idx];
    d61[idx] = a;
}

// ---------------- K7: adj_t row, v, g, pre-gates per (b,t) ----------------
__global__ __launch_bounds__(256) void k_g(const float* __restrict__ x, const float* __restrict__ d61,
    const float* __restrict__ adjr, const float* __restrict__ gcn_w, const float* __restrict__ gcn_b,
    const float* __restrict__ w_r, const float* __restrict__ w_u, const float* __restrict__ w_c,
    float* __restrict__ preR, float* __restrict__ preU, float* __restrict__ preC)
{
    __shared__ float adjt[Cc];
    __shared__ float v[Ll];
    __shared__ float g[GRU];
    int bt = blockIdx.x, t = bt >> 6, b = bt & 63;
    int m = b * Ss + t;
    int tid = threadIdx.x;
    if (tid < Cc) {
        float sv = d61[(size_t)m*Cc + tid] + adjr[b*Cc + tid];
        adjt[tid] = 1.f / (1.f + expf(-sv));
    }
    __syncthreads();
    if (tid < Ll) {
        const float* xp = x + (size_t)m*CL + tid;
        float acc = 0.f;
        for (int j = 0; j < Cc; ++j) acc += adjt[j] * xp[j*Ll];
        v[tid] = acc;
    }
    __syncthreads();
    if (tid < GRU) {
        float acc = gcn_b[tid];
        for (int l = 0; l < Ll; ++l) acc += v[l] * gcn_w[l*GRU + tid];
        g[tid] = acc;
    }
    __syncthreads();
    if (tid < GRU) {
        float ar = 0.f, au = 0.f, ac = 0.f;
        for (int i = 0; i < GRU; ++i) {
            float gi = g[i];
            ar += gi * w_r[i*GRU + tid];
            au += gi * w_u[i*GRU + tid];
            ac += gi * w_c[i*GRU + tid];
        }
        preR[(size_t)bt*GRU + tid] = ar;
        preU[(size_t)bt*GRU + tid] = au;
        preC[(size_t)bt*GRU + tid] = ac;
    }
}

// ---------------- K8: GRU scan over t ----------------
__global__ __launch_bounds__(64) void k_gru(const float* __restrict__ preR, const float* __restrict__ preU,
    const float* __restrict__ preC,
    const float* __restrict__ w_r, const float* __restrict__ wb_r,
    const float* __restrict__ w_u, const float* __restrict__ wb_u,
    const float* __restrict__ w_c, const float* __restrict__ wb_c,
    const float* __restrict__ b_r, const float* __restrict__ b_u, const float* __restrict__ b_c,
    float* __restrict__ out)
{
    __shared__ float W2r[GRU*GRU], W2u[GRU*GRU], W2c[GRU*GRU];
    __shared__ float h[GRU], rh[GRU];
    int b = blockIdx.x, o = threadIdx.x;
    for (int i = 0; i < GRU; ++i) {
        W2r[i*GRU + o] = w_r[(GRU + i)*GRU + o];
        W2u[i*GRU + o] = w_u[(GRU + i)*GRU + o];
        W2c[i*GRU + o] = w_c[(GRU + i)*GRU + o];
    }
    float cr = wb_r[o] + b_r[o];
    float cu = wb_u[o] + b_u[o];
    float cc = wb_c[o] + b_c[o];
    float hreg = 0.f;
    h[o] = 0.f;
    __syncthreads();
    for (int t = 0; t < Ss; ++t) {
        size_t base = (size_t)(t*Bb + b)*GRU + o;
        float ar = preR[base] + cr;
        float au = preU[base] + cu;
        for (int i = 0; i < GRU; ++i) {
            float hi = h[i];
            ar += hi * W2r[i*GRU + o];
            au += hi * W2u[i*GRU + o];
        }
        float r = 1.f / (1.f + expf(-ar));
        float u = 1.f / (1.f + expf(-au));
        rh[o] = r * hreg;
        __syncthreads();
        float ac = preC[base] + cc;
        for (int i = 0; i < GRU; ++i) ac += rh[i] * W2c[i*GRU + o];
        float ct = tanhf(ac);
        hreg = u * hreg + (1.f - u) * ct;
        __syncthreads();
        h[o] = hreg;
        __syncthreads();
    }
    out[b*GRU + o] = hreg;
}

// ---------------- launcher ----------------
extern "C" void kernel_launch(void* const* d_in, const int* in_sizes, int n_in,
                              void* d_out, int out_size, void* d_ws, size_t ws_size,
                              hipStream_t stream)
{
    const float* x     = (const float*)d_in[0];
    const float* se_w1 = (const float*)d_in[1];
    const float* se_w2 = (const float*)d_in[2];
    const float* dwk1  = (const float*)d_in[3];
    const float* dwb1  = (const float*)d_in[4];
    const float* pwk1  = (const float*)d_in[5];
    const float* pwb1  = (const float*)d_in[6];
    const float* dwk2  = (const float*)d_in[7];
    const float* dwb2  = (const float*)d_in[8];
    const float* pwk2  = (const float*)d_in[9];
    const float* pwb2  = (const float*)d_in[10];
    const float* dwk3  = (const float*)d_in[11];
    const float* dwb3  = (const float*)d_in[12];
    const float* pwk3  = (const float*)d_in[13];
    const float* pwb3  = (const float*)d_in[14];
    const float* gcn_w = (const float*)d_in[15];
    const float* gcn_b = (const float*)d_in[16];
    const float* w_r   = (const float*)d_in[17];
    const float* wb_r  = (const float*)d_in[18];
    const float* w_u   = (const float*)d_in[19];
    const float* wb_u  = (const float*)d_in[20];
    const float* w_c   = (const float*)d_in[21];
    const float* wb_c  = (const float*)d_in[22];
    const float* b_r   = (const float*)d_in[23];
    const float* b_u   = (const float*)d_in[24];
    const float* b_c   = (const float*)d_in[25];
    float* out = (float*)d_out;

    // workspace (floats). msb/f_re/f_im region (3x670592 = 2,011,776) is dead
    // after k_adjrow; P (16*119040 = 1,904,640) aliases it. No Hbig buffer.
    float* ws   = (float*)d_ws;
    float* sq   = ws;                    // 1920
    float* aw   = sq   + 1920;           // 1920
    float* msb  = aw   + 1920;           // 670592
    float* f_re = msb  + 670592;         // 670592
    float* f_im = f_re + 670592;         // 670592
    float* adjr = f_im + 670592;         // 3968
    float* d61  = adjr + 3968;           // 119040
    float* preR = d61  + 119040;         // 122880
    float* preU = preR + 122880;         // 122880
    float* preC = preU + 122880;         // 122880
    float* Heff = preC + 122880;         // 6696
    float* Ccst = Heff + 6696;           // 8
    float* P    = msb;                   // alias (1,904,640 <= 2,011,776)

    k_sq<<<Bb*Ss, 256, 0, stream>>>(x, sq);
    k_se<<<1, 64, 0, stream>>>(sq, se_w1, se_w2, aw);
    k_maxseg<<<(Bb*CL + 255)/256, 256, 0, stream>>>(x, aw, msb);
    k_dft<<<Bb*Cc, 192, 0, stream>>>(msb, f_re, f_im);
    k_adjrow<<<Bb*Cc, 64, 0, stream>>>(f_re, f_im, adjr);
    k_heff<<<1, 256, 0, stream>>>(dwk1, dwb1, pwk1, pwb1, dwk2, dwb2, pwk2, pwb2,
                                  dwk3, dwb3, pwk3, pwb3, Heff, Ccst);
    k_gemm<<<(1920/MT)*KSPLIT, 256, 0, stream>>>(x, Heff, P);
    k_dred<<<(1920*Cc + 255)/256, 256, 0, stream>>>(P, Ccst, d61);
    k_g<<<Ss*Bb, 256, 0, stream>>>(x, d61, adjr, gcn_w, gcn_b, w_r, w_u, w_c, preR, preU, preC);
    k_gru<<<Bb, 64, 0, stream>>>(preR, preU, preC, w_r, wb_r, w_u, wb_u, w_c, wb_c,
                                 b_r, b_u, b_c, out);
}

// Round 6
// 299.828 us; speedup vs baseline: 7.1813x; 1.4115x over previous
//
#include <hip/hip_runtime.h>
#include <hip/hip_bf16.h>
#include <math.h>

#define Bb 64
#define Ss 30
#define Cc 62
#define Ll 169
#define CL (Cc*Ll)          // 10478
#define GRU 64
#define HTAPS 108           // 64+32+14-2
#define MT 32               // GEMM M tile
#define KSPLIT 16
#define KSLICE 656          // 16*656 >= 10478
#define SUBK 64
#define XS_STRIDE 68        // mult of 4 for float4 reads

// ---------------- K1: sq[b,s] = mean over (c,L) ----------------
__global__ __launch_bounds__(256) void k_sq(const float* __restrict__ x, float* __restrict__ sq)
{
    __shared__ float red[4];
    int bs = blockIdx.x;
    const float* p = x + (size_t)bs * CL;
    float acc = 0.f;
    for (int i = threadIdx.x; i < CL; i += 256) acc += p[i];
    for (int off = 32; off; off >>= 1) acc += __shfl_down(acc, off);
    if ((threadIdx.x & 63) == 0) red[threadIdx.x >> 6] = acc;
    __syncthreads();
    if (threadIdx.x == 0) sq[bs] = (red[0] + red[1] + red[2] + red[3]) / (float)CL;
}

// ---------------- K2: SE MLP -> a[b,s] ----------------
__global__ __launch_bounds__(64) void k_se(const float* __restrict__ sq, const float* __restrict__ w1,
                                           const float* __restrict__ w2, float* __restrict__ aout)
{
    int b = threadIdx.x;
    float hid[15];
#pragma unroll
    for (int j = 0; j < 15; ++j) {
        float h = 0.f;
        for (int s = 0; s < Ss; ++s) h += sq[b*Ss + s] * w1[s*15 + j];
        hid[j] = fmaxf(h, 0.f);
    }
    for (int s = 0; s < Ss; ++s) {
        float o = 0.f;
#pragma unroll
        for (int j = 0; j < 15; ++j) o += hid[j] * w2[j*Ss + s];
        aout[b*Ss + s] = 1.f / (1.f + expf(-o));
    }
}

// ---------------- K3: max_seg[b,c,l] = max_s a[b,s]*x[b,s,c,l] ----------------
__global__ __launch_bounds__(256) void k_maxseg(const float* __restrict__ x, const float* __restrict__ a,
                                                float* __restrict__ ms)
{
    int idx = blockIdx.x * 256 + threadIdx.x;
    if (idx >= Bb*CL) return;
    int b = idx / CL;
    int rem = idx - b*CL;
    float m = -INFINITY;
    for (int s = 0; s < Ss; ++s) {
        float v = x[(size_t)(b*Ss + s)*CL + rem] * a[b*Ss + s];
        m = fmaxf(m, v);
    }
    ms[idx] = m;
}

// ---------------- K4: direct DFT per (b,c) row ----------------
__global__ __launch_bounds__(192) void k_dft(const float* __restrict__ ms, float* __restrict__ fre,
                                             float* __restrict__ fim)
{
    __shared__ float xr[Ll], ct[Ll], st[Ll];
    int row = blockIdx.x;
    int tid = threadIdx.x;
    if (tid < Ll) {
        xr[tid] = ms[(size_t)row*Ll + tid];
        float ang = (float)tid * (6.28318530717958647692f / (float)Ll);
        ct[tid] = cosf(ang);
        st[tid] = sinf(ang);
    }
    __syncthreads();
    if (tid < Ll) {
        int k = tid;
        float re = 0.f, im = 0.f;
        int idx = 0;
        for (int n = 0; n < Ll; ++n) {
            float v = xr[n];
            re += v * ct[idx];
            im -= v * st[idx];
            idx += k; if (idx >= Ll) idx -= Ll;
        }
        fre[(size_t)row*Ll + k] = re;
        fim[(size_t)row*Ll + k] = im;
    }
}

// ---------------- K5: adj row 61 ----------------
__global__ __launch_bounds__(64) void k_adjrow(const float* __restrict__ fre, const float* __restrict__ fim,
                                               float* __restrict__ adjr)
{
    int b = blockIdx.x / Cc;
    int j = blockIdx.x % Cc;
    int lane = threadIdx.x;
    const float* re61 = fre + (size_t)(b*Cc + 61)*Ll;
    const float* im61 = fim + (size_t)(b*Cc + 61)*Ll;
    const float* rej  = fre + (size_t)(b*Cc + j)*Ll;
    const float* imj  = fim + (size_t)(b*Cc + j)*Ll;
    float num = 0.f, den = 0.f;
    for (int l = lane; l < Ll; l += 64) {
        float ar = re61[l], ai = im61[l];
        float br = rej[l],  bi = imj[l];
        num += ai*br - ar*bi;
        den += sqrtf(ar*ar + ai*ai) * sqrtf(br*br + bi*bi);
    }
    for (int off = 32; off; off >>= 1) { num += __shfl_down(num, off); den += __shfl_down(den, off); }
    if (lane == 0) adjr[b*Cc + j] = (j == 61) ? 0.f : num / den;
}

// ---------------- K6a1: per-e F then G (62 blocks) ----------------
// F[e][t] = sum_f pwk3[61,f]*pwk2[f,e]*dwk3[f,t];  G[e][s] = (F[e] conv dwk2[e])[s]
__global__ __launch_bounds__(64) void k_fg(const float* __restrict__ pwk2, const float* __restrict__ pwk3,
                                           const float* __restrict__ dwk2, const float* __restrict__ dwk3,
                                           float* __restrict__ Gout)
{
    __shared__ float q[Cc], p2c[Cc], F[14], k2[32];
    int e = blockIdx.x, t = threadIdx.x;
    if (t < Cc) { q[t] = pwk3[61*Cc + t]; p2c[t] = pwk2[t*Cc + e]; }
    if (t < 32) k2[t] = dwk2[e*32 + t];
    __syncthreads();
    if (t < 14) {
        float acc = 0.f;
        for (int f = 0; f < Cc; ++f) acc += q[f] * p2c[f] * dwk3[f*14 + t];
        F[t] = acc;
    }
    __syncthreads();
    if (t < 45) {
        float acc = 0.f;
        int t0 = t - 31; if (t0 < 0) t0 = 0;
        int t1 = t; if (t1 > 13) t1 = 13;
        for (int tt = t0; tt <= t1; ++tt) acc += F[tt] * k2[t - tt];
        Gout[e*45 + t] = acc;
    }
}

// ---------------- K6a2: per-c H1 then Heff (62 blocks) ----------------
// H1[c][s] = sum_e pwk1[e,c]*G[e][s];  Heff[c][a] = (H1[c] conv dwk1[c])[a]
__global__ __launch_bounds__(128) void k_h1h(const float* __restrict__ pwk1, const float* __restrict__ dwk1,
                                             const float* __restrict__ Gin, float* __restrict__ Heff)
{
    __shared__ float p1c[Cc], H1[45], k1[64];
    int c = blockIdx.x, t = threadIdx.x;
    if (t < Cc) p1c[t] = pwk1[t*Cc + c];
    if (t >= 64 && t < 128) k1[t - 64] = dwk1[c*64 + (t - 64)];
    __syncthreads();
    if (t < 45) {
        float acc = 0.f;
        for (int e = 0; e < Cc; ++e) acc += p1c[e] * Gin[e*45 + t];
        H1[t] = acc;
    }
    __syncthreads();
    if (t < HTAPS) {
        float acc = 0.f;
        int s0 = t - 63; if (s0 < 0) s0 = 0;
        int s1 = t; if (s1 > 44) s1 = 44;
        for (int s = s0; s <= s1; ++s) acc += H1[s] * k1[t - s];
        Heff[c*HTAPS + t] = acc;
    }
}

// ---------------- K6a3: bias constant C ----------------
__global__ __launch_bounds__(64) void k_cc(const float* __restrict__ pwk1, const float* __restrict__ pwb1,
                                           const float* __restrict__ dwb1,
                                           const float* __restrict__ dwk2, const float* __restrict__ dwb2,
                                           const float* __restrict__ pwk2, const float* __restrict__ pwb2,
                                           const float* __restrict__ dwk3, const float* __restrict__ dwb3,
                                           const float* __restrict__ pwk3, const float* __restrict__ pwb3,
                                           float* __restrict__ Ccst)
{
    __shared__ float db1[Cc], cA[Cc], cB[Cc];
    int t = threadIdx.x;
    if (t < Cc) db1[t] = dwb1[t];
    __syncthreads();
    if (t < Cc) {
        float acc = pwb1[t];
        for (int c = 0; c < Cc; ++c) acc += pwk1[t*Cc + c] * db1[c];
        float sk = 0.f;
        for (int a = 0; a < 32; ++a) sk += dwk2[t*32 + a];
        cA[t] = acc * sk + dwb2[t];
    }
    __syncthreads();
    if (t < Cc) {
        float acc = pwb2[t];
        for (int e = 0; e < Cc; ++e) acc += pwk2[t*Cc + e] * cA[e];
        float sk = 0.f;
        for (int tt = 0; tt < 14; ++tt) sk += dwk3[t*14 + tt];
        cB[t] = acc * sk + dwb3[t];
    }
    __syncthreads();
    float v = (t < Cc) ? pwk3[61*Cc + t] * cB[t] : 0.f;
    for (int off = 32; off; off >>= 1) v += __shfl_down(v, off);
    if (t == 0) Ccst[0] = v + pwb3[61];
}

// ---------------- K6c: GEMM  P[ks][1920][62] = X[.,kslice] * H(kslice,.) ----------------
__global__ __launch_bounds__(256) void k_gemm(const float* __restrict__ x,
                                              const float* __restrict__ Heff,
                                              float* __restrict__ P)
{
    __shared__ __align__(16) float Xs[MT * XS_STRIDE];  // 32x64 (stride 68)
    __shared__ __align__(16) float Hs[SUBK * 64];       // 64x64 (cols 62 + zero pad)
    const int tid = threadIdx.x;
    const int mt = blockIdx.x % (1920 / MT);            // 60 M tiles
    const int ks = blockIdx.x / (1920 / MT);            // 16 K splits
    const int k0 = ks * KSLICE;
    const int kend = (k0 + KSLICE < CL) ? (k0 + KSLICE) : CL;
    const int m0g = mt * MT;
    const int n0 = (tid & 15) * 4;
    const int mg = tid >> 4;                            // 0..15

    float acc[2][4];
#pragma unroll
    for (int i = 0; i < 2; ++i) { acc[i][0]=0.f; acc[i][1]=0.f; acc[i][2]=0.f; acc[i][3]=0.f; }

    for (int kb = k0; kb < kend; kb += SUBK) {
        for (int u = tid; u < MT*32; u += 256) {
            int r = u >> 5, c2 = u & 31;
            int col = kb + 2*c2;
            float2 v = make_float2(0.f, 0.f);
            if (col < kend) v = *reinterpret_cast<const float2*>(x + (size_t)(m0g + r)*CL + col);
            Xs[r*XS_STRIDE + 2*c2]     = v.x;
            Xs[r*XS_STRIDE + 2*c2 + 1] = v.y;
        }
        for (int u = tid; u < SUBK*64; u += 256) {
            int r = u >> 6, j = u & 63;
            int kg = kb + r;
            float hv = 0.f;
            if (j < Cc && kg < kend) {
                int c = kg / Ll, l = kg - c * Ll;
                int a = l - j;
                if (a >= 0 && a < HTAPS) hv = Heff[c*HTAPS + a];
            }
            Hs[u] = hv;
        }
        __syncthreads();
        for (int kk = 0; kk < SUBK; kk += 4) {
            const float4 hv0 = *reinterpret_cast<const float4*>(&Hs[(kk+0)*64 + n0]);
            const float4 hv1 = *reinterpret_cast<const float4*>(&Hs[(kk+1)*64 + n0]);
            const float4 hv2 = *reinterpret_cast<const float4*>(&Hs[(kk+2)*64 + n0]);
            const float4 hv3 = *reinterpret_cast<const float4*>(&Hs[(kk+3)*64 + n0]);
#pragma unroll
            for (int i = 0; i < 2; ++i) {
                const float4 xv = *reinterpret_cast<const float4*>(&Xs[(mg + 16*i)*XS_STRIDE + kk]);
                acc[i][0] += xv.x*hv0.x + xv.y*hv1.x + xv.z*hv2.x + xv.w*hv3.x;
                acc[i][1] += xv.x*hv0.y + xv.y*hv1.y + xv.z*hv2.y + xv.w*hv3.y;
                acc[i][2] += xv.x*hv0.z + xv.y*hv1.z + xv.z*hv2.z + xv.w*hv3.z;
                acc[i][3] += xv.x*hv0.w + xv.y*hv1.w + xv.z*hv2.w + xv.w*hv3.w;
            }
        }
        __syncthreads();
    }
#pragma unroll
    for (int i = 0; i < 2; ++i) {
        int row = m0g + mg + 16*i;
        float* dst = P + (size_t)(ks*1920 + row)*Cc + n0;
#pragma unroll
        for (int q = 0; q < 4; ++q)
            if (n0 + q < Cc) dst[q] = acc[i][q];
    }
}

// ---------------- K6d: reduce partials -> d61[m][j] (m = b*30+t) ----------------
__global__ __launch_bounds__(256) void k_dred(const float* __restrict__ P,
                                              const float* __restrict__ Cconst,
                                              float* __restrict__ d61)
{
    int idx = blockIdx.x * 256 + threadIdx.x;
    if (idx >= 1920 * Cc) return;
    float a = Cconst[0];
#pragma unroll
    for (int ks = 0; ks < KSPLIT; ++ks) a += P[(size_t)ks * (1920*Cc) + idx];
    d61[idx] = a;
}

// ---------------- K7: adj_t row, v, g, pre-gates per (b,t) ----------------
__global__ __launch_bounds__(256) void k_g(const float* __restrict__ x, const float* __restrict__ d61,
    const float* __restrict__ adjr, const float* __restrict__ gcn_w, const float* __restrict__ gcn_b,
    const float* __restrict__ w_r, const float* __restrict__ w_u, const float* __restrict__ w_c,
    float* __restrict__ preR, float* __restrict__ preU, float* __restrict__ preC)
{
    __shared__ float adjt[Cc];
    __shared__ float v[Ll];
    __shared__ float g[GRU];
    int bt = blockIdx.x, t = bt >> 6, b = bt & 63;
    int m = b * Ss + t;
    int tid = threadIdx.x;
    if (tid < Cc) {
        float sv = d61[(size_t)m*Cc + tid] + adjr[b*Cc + tid];
        adjt[tid] = 1.f / (1.f + expf(-sv));
    }
    __syncthreads();
    if (tid < Ll) {
        const float* xp = x + (size_t)m*CL + tid;
        float acc = 0.f;
        for (int j = 0; j < Cc; ++j) acc += adjt[j] * xp[j*Ll];
        v[tid] = acc;
    }
    __syncthreads();
    if (tid < GRU) {
        float acc = gcn_b[tid];
        for (int l = 0; l < Ll; ++l) acc += v[l] * gcn_w[l*GRU + tid];
        g[tid] = acc;
    }
    __syncthreads();
    if (tid < GRU) {
        float ar = 0.f, au = 0.f, ac = 0.f;
        for (int i = 0; i < GRU; ++i) {
            float gi = g[i];
            ar += gi * w_r[i*GRU + tid];
            au += gi * w_u[i*GRU + tid];
            ac += gi * w_c[i*GRU + tid];
        }
        preR[(size_t)bt*GRU + tid] = ar;
        preU[(size_t)bt*GRU + tid] = au;
        preC[(size_t)bt*GRU + tid] = ac;
    }
}

// ---------------- K8: GRU scan over t ----------------
__global__ __launch_bounds__(64) void k_gru(const float* __restrict__ preR, const float* __restrict__ preU,
    const float* __restrict__ preC,
    const float* __restrict__ w_r, const float* __restrict__ wb_r,
    const float* __restrict__ w_u, const float* __restrict__ wb_u,
    const float* __restrict__ w_c, const float* __restrict__ wb_c,
    const float* __restrict__ b_r, const float* __restrict__ b_u, const float* __restrict__ b_c,
    float* __restrict__ out)
{
    __shared__ float W2r[GRU*GRU], W2u[GRU*GRU], W2c[GRU*GRU];
    __shared__ float h[GRU], rh[GRU];
    int b = blockIdx.x, o = threadIdx.x;
    for (int i = 0; i < GRU; ++i) {
        W2r[i*GRU + o] = w_r[(GRU + i)*GRU + o];
        W2u[i*GRU + o] = w_u[(GRU + i)*GRU + o];
        W2c[i*GRU + o] = w_c[(GRU + i)*GRU + o];
    }
    float cr = wb_r[o] + b_r[o];
    float cu = wb_u[o] + b_u[o];
    float cc = wb_c[o] + b_c[o];
    float hreg = 0.f;
    h[o] = 0.f;
    __syncthreads();
    for (int t = 0; t < Ss; ++t) {
        size_t base = (size_t)(t*Bb + b)*GRU + o;
        float ar = preR[base] + cr;
        float au = preU[base] + cu;
        for (int i = 0; i < GRU; ++i) {
            float hi = h[i];
            ar += hi * W2r[i*GRU + o];
            au += hi * W2u[i*GRU + o];
        }
        float r = 1.f / (1.f + expf(-ar));
        float u = 1.f / (1.f + expf(-au));
        rh[o] = r * hreg;
        __syncthreads();
        float ac = preC[base] + cc;
        for (int i = 0; i < GRU; ++i) ac += rh[i] * W2c[i*GRU + o];
        float ct = tanhf(ac);
        hreg = u * hreg + (1.f - u) * ct;
        __syncthreads();
        h[o] = hreg;
        __syncthreads();
    }
    out[b*GRU + o] = hreg;
}

// ---------------- launcher ----------------
extern "C" void kernel_launch(void* const* d_in, const int* in_sizes, int n_in,
                              void* d_out, int out_size, void* d_ws, size_t ws_size,
                              hipStream_t stream)
{
    const float* x     = (const float*)d_in[0];
    const float* se_w1 = (const float*)d_in[1];
    const float* se_w2 = (const float*)d_in[2];
    const float* dwk1  = (const float*)d_in[3];
    const float* dwb1  = (const float*)d_in[4];
    const float* pwk1  = (const float*)d_in[5];
    const float* pwb1  = (const float*)d_in[6];
    const float* dwk2  = (const float*)d_in[7];
    const float* dwb2  = (const float*)d_in[8];
    const float* pwk2  = (const float*)d_in[9];
    const float* pwb2  = (const float*)d_in[10];
    const float* dwk3  = (const float*)d_in[11];
    const float* dwb3  = (const float*)d_in[12];
    const float* pwk3  = (const float*)d_in[13];
    const float* pwb3  = (const float*)d_in[14];
    const float* gcn_w = (const float*)d_in[15];
    const float* gcn_b = (const float*)d_in[16];
    const float* w_r   = (const float*)d_in[17];
    const float* wb_r  = (const float*)d_in[18];
    const float* w_u   = (const float*)d_in[19];
    const float* wb_u  = (const float*)d_in[20];
    const float* w_c   = (const float*)d_in[21];
    const float* wb_c  = (const float*)d_in[22];
    const float* b_r   = (const float*)d_in[23];
    const float* b_u   = (const float*)d_in[24];
    const float* b_c   = (const float*)d_in[25];
    float* out = (float*)d_out;

    // workspace (floats). msb/f_re/f_im region (3x670592 = 2,011,776) is dead
    // after k_adjrow; P (16*119040 = 1,904,640) aliases it.
    float* ws   = (float*)d_ws;
    float* sq   = ws;                    // 1920
    float* aw   = sq   + 1920;           // 1920
    float* msb  = aw   + 1920;           // 670592
    float* f_re = msb  + 670592;         // 670592
    float* f_im = f_re + 670592;         // 670592
    float* adjr = f_im + 670592;         // 3968
    float* d61  = adjr + 3968;           // 119040
    float* preR = d61  + 119040;         // 122880
    float* preU = preR + 122880;         // 122880
    float* preC = preU + 122880;         // 122880
    float* Heff = preC + 122880;         // 6696
    float* Ccst = Heff + 6696;           // 8
    float* Gbuf = Ccst + 8;              // 2790
    float* P    = msb;                   // alias (1,904,640 <= 2,011,776)

    k_sq<<<Bb*Ss, 256, 0, stream>>>(x, sq);
    k_se<<<1, 64, 0, stream>>>(sq, se_w1, se_w2, aw);
    k_maxseg<<<(Bb*CL + 255)/256, 256, 0, stream>>>(x, aw, msb);
    k_dft<<<Bb*Cc, 192, 0, stream>>>(msb, f_re, f_im);
    k_adjrow<<<Bb*Cc, 64, 0, stream>>>(f_re, f_im, adjr);
    k_fg<<<Cc, 64, 0, stream>>>(pwk2, pwk3, dwk2, dwk3, Gbuf);
    k_h1h<<<Cc, 128, 0, stream>>>(pwk1, dwk1, Gbuf, Heff);
    k_cc<<<1, 64, 0, stream>>>(pwk1, pwb1, dwb1, dwk2, dwb2, pwk2, pwb2,
                               dwk3, dwb3, pwk3, pwb3, Ccst);
    k_gemm<<<(1920/MT)*KSPLIT, 256, 0, stream>>>(x, Heff, P);
    k_dred<<<(1920*Cc + 255)/256, 256, 0, stream>>>(P, Ccst, d61);
    k_g<<<Ss*Bb, 256, 0, stream>>>(x, d61, adjr, gcn_w, gcn_b, w_r, w_u, w_c, preR, preU, preC);
    k_gru<<<Bb, 64, 0, stream>>>(preR, preU, preC, w_r, wb_r, w_u, wb_u, w_c, wb_c,
                                 b_r, b_u, b_c, out);
}

// Round 7
// 206.368 us; speedup vs baseline: 10.4335x; 1.4529x over previous
//
#include <hip/hip_runtime.h>
#include <hip/hip_bf16.h>
#include <math.h>

#define Bb 64
#define Ss 30
#define Cc 62
#define Ll 169
#define CL (Cc*Ll)          // 10478
#define GRU 64
#define HTAPS 108           // 64+32+14-2
#define KSPLIT 16
#define KSLICE 656          // 16*656 >= 10478
#define TS 344              // twiddle row stride (cos 169 | -sin 169 | pad)

typedef __attribute__((ext_vector_type(8))) short short8;
typedef __attribute__((ext_vector_type(4))) float f32x4;

__device__ __forceinline__ unsigned short f2bf(float f)
{
    union { float f; unsigned int u; } v; v.f = f;
    unsigned int u = v.u + 0x7fffu + ((v.u >> 16) & 1u);   // RNE
    return (unsigned short)(u >> 16);
}

// ---------------- K1: sq[b,s] = mean over (c,L) ----------------
__global__ __launch_bounds__(256) void k_sq(const float* __restrict__ x, float* __restrict__ sq)
{
    __shared__ float red[4];
    int bs = blockIdx.x;
    const float* p = x + (size_t)bs * CL;
    float acc = 0.f;
    for (int i = threadIdx.x; i < CL; i += 256) acc += p[i];
    for (int off = 32; off; off >>= 1) acc += __shfl_down(acc, off);
    if ((threadIdx.x & 63) == 0) red[threadIdx.x >> 6] = acc;
    __syncthreads();
    if (threadIdx.x == 0) sq[bs] = (red[0] + red[1] + red[2] + red[3]) / (float)CL;
}

// ---------------- K2: SE MLP -> a[b,s] ----------------
__global__ __launch_bounds__(64) void k_se(const float* __restrict__ sq, const float* __restrict__ w1,
                                           const float* __restrict__ w2, float* __restrict__ aout)
{
    int b = threadIdx.x;
    float hid[15];
#pragma unroll
    for (int j = 0; j < 15; ++j) {
        float h = 0.f;
        for (int s = 0; s < Ss; ++s) h += sq[b*Ss + s] * w1[s*15 + j];
        hid[j] = fmaxf(h, 0.f);
    }
    for (int s = 0; s < Ss; ++s) {
        float o = 0.f;
#pragma unroll
        for (int j = 0; j < 15; ++j) o += hid[j] * w2[j*Ss + s];
        aout[b*Ss + s] = 1.f / (1.f + expf(-o));
    }
}

// ---------------- K3: max_seg[b,c,l] = max_s a[b,s]*x[b,s,c,l] ----------------
__global__ __launch_bounds__(256) void k_maxseg(const float* __restrict__ x, const float* __restrict__ a,
                                                float* __restrict__ ms)
{
    int idx = blockIdx.x * 256 + threadIdx.x;
    if (idx >= Bb*CL) return;
    int b = idx / CL;
    int rem = idx - b*CL;
    float m = -INFINITY;
    for (int s = 0; s < Ss; ++s) {
        float v = x[(size_t)(b*Ss + s)*CL + rem] * a[b*Ss + s];
        m = fmaxf(m, v);
    }
    ms[idx] = m;
}

// ---------------- K4a: twiddle table T[n][col]: col<169 cos(2pi n col/169); 169..337 -sin ----------------
__global__ __launch_bounds__(256) void k_tw(float* __restrict__ T)
{
    int idx = blockIdx.x * 256 + threadIdx.x;
    if (idx >= Ll * TS) return;
    int n = idx / TS, col = idx - n * TS;
    float v = 0.f;
    if (col < 338) {
        int kp = (col < Ll) ? col : col - Ll;
        int m = (n * kp) % Ll;
        float ang = 6.28318530717958647692f * (float)m / (float)Ll;
        v = (col < Ll) ? cosf(ang) : -sinf(ang);
    }
    T[idx] = v;
}

// ---------------- K4b: DFT as GEMM  F[3968][338] = ms[3968][169] * T[169][338] ----------------
__global__ __launch_bounds__(256) void k_dftg(const float* __restrict__ ms, const float* __restrict__ T,
                                              float* __restrict__ fre, float* __restrict__ fim)
{
    __shared__ __align__(16) float As[64*68];
    __shared__ __align__(16) float Bs[64*68];
    const int tid = threadIdx.x;
    const int mtile = blockIdx.x % 62;
    const int ntile = blockIdx.x / 62;           // 0..5
    const int m0 = mtile * 64, n0g = ntile * 64;
    const int tn = tid & 15, tm = tid >> 4;      // 16 n-groups x 16 m-threads
    const int n0 = tn * 4;
    const int sr = tid >> 2, sq4 = (tid & 3) * 16;

    float acc[4][4];
#pragma unroll
    for (int i = 0; i < 4; ++i)
#pragma unroll
        for (int q = 0; q < 4; ++q) acc[i][q] = 0.f;

    for (int kb = 0; kb < 192; kb += 64) {
        // stage A: rows m0+sr, k = kb+sq4 .. +15 (scalar: 169-stride rows unaligned)
        {
            const float* ap = ms + (size_t)(m0 + sr)*Ll;
#pragma unroll
            for (int t = 0; t < 16; ++t) {
                int k = kb + sq4 + t;
                As[sr*68 + sq4 + t] = (k < Ll) ? ap[k] : 0.f;
            }
        }
        // stage B: Bs[kk][j] = T[kb+kk][n0g+j]
        {
            int kkg = kb + sr;
#pragma unroll
            for (int t = 0; t < 16; ++t) {
                int col = n0g + sq4 + t;
                Bs[sr*68 + sq4 + t] = (kkg < Ll && col < TS) ? T[kkg*TS + col] : 0.f;
            }
        }
        __syncthreads();
        for (int kk = 0; kk < 64; kk += 4) {
            const float4 b0 = *reinterpret_cast<const float4*>(&Bs[(kk+0)*68 + n0]);
            const float4 b1 = *reinterpret_cast<const float4*>(&Bs[(kk+1)*68 + n0]);
            const float4 b2 = *reinterpret_cast<const float4*>(&Bs[(kk+2)*68 + n0]);
            const float4 b3 = *reinterpret_cast<const float4*>(&Bs[(kk+3)*68 + n0]);
#pragma unroll
            for (int i = 0; i < 4; ++i) {
                const float4 av = *reinterpret_cast<const float4*>(&As[(tm + 16*i)*68 + kk]);
                acc[i][0] += av.x*b0.x + av.y*b1.x + av.z*b2.x + av.w*b3.x;
                acc[i][1] += av.x*b0.y + av.y*b1.y + av.z*b2.y + av.w*b3.y;
                acc[i][2] += av.x*b0.z + av.y*b1.z + av.z*b2.z + av.w*b3.z;
                acc[i][3] += av.x*b0.w + av.y*b1.w + av.z*b2.w + av.w*b3.w;
            }
        }
        __syncthreads();
    }
#pragma unroll
    for (int i = 0; i < 4; ++i) {
        int row = m0 + tm + 16*i;
#pragma unroll
        for (int q = 0; q < 4; ++q) {
            int col = n0g + n0 + q;
            if (col < Ll)        fre[(size_t)row*Ll + col] = acc[i][q];
            else if (col < 338)  fim[(size_t)row*Ll + (col - Ll)] = acc[i][q];
        }
    }
}

// ---------------- K5: adj row 61 ----------------
__global__ __launch_bounds__(64) void k_adjrow(const float* __restrict__ fre, const float* __restrict__ fim,
                                               float* __restrict__ adjr)
{
    int b = blockIdx.x / Cc;
    int j = blockIdx.x % Cc;
    int lane = threadIdx.x;
    const float* re61 = fre + (size_t)(b*Cc + 61)*Ll;
    const float* im61 = fim + (size_t)(b*Cc + 61)*Ll;
    const float* rej  = fre + (size_t)(b*Cc + j)*Ll;
    const float* imj  = fim + (size_t)(b*Cc + j)*Ll;
    float num = 0.f, den = 0.f;
    for (int l = lane; l < Ll; l += 64) {
        float ar = re61[l], ai = im61[l];
        float br = rej[l],  bi = imj[l];
        num += ai*br - ar*bi;
        den += sqrtf(ar*ar + ai*ai) * sqrtf(br*br + bi*bi);
    }
    for (int off = 32; off; off >>= 1) { num += __shfl_down(num, off); den += __shfl_down(den, off); }
    if (lane == 0) adjr[b*Cc + j] = (j == 61) ? 0.f : num / den;
}

// ---------------- K6a1: per-e F then G (62 blocks) ----------------
__global__ __launch_bounds__(64) void k_fg(const float* __restrict__ pwk2, const float* __restrict__ pwk3,
                                           const float* __restrict__ dwk2, const float* __restrict__ dwk3,
                                           float* __restrict__ Gout)
{
    __shared__ float q[Cc], p2c[Cc], F[14], k2[32];
    int e = blockIdx.x, t = threadIdx.x;
    if (t < Cc) { q[t] = pwk3[61*Cc + t]; p2c[t] = pwk2[t*Cc + e]; }
    if (t < 32) k2[t] = dwk2[e*32 + t];
    __syncthreads();
    if (t < 14) {
        float acc = 0.f;
        for (int f = 0; f < Cc; ++f) acc += q[f] * p2c[f] * dwk3[f*14 + t];
        F[t] = acc;
    }
    __syncthreads();
    if (t < 45) {
        float acc = 0.f;
        int t0 = t - 31; if (t0 < 0) t0 = 0;
        int t1 = t; if (t1 > 13) t1 = 13;
        for (int tt = t0; tt <= t1; ++tt) acc += F[tt] * k2[t - tt];
        Gout[e*45 + t] = acc;
    }
}

// ---------------- K6a2: per-c H1 then Heff (62 blocks) ----------------
__global__ __launch_bounds__(128) void k_h1h(const float* __restrict__ pwk1, const float* __restrict__ dwk1,
                                             const float* __restrict__ Gin, float* __restrict__ Heff)
{
    __shared__ float p1c[Cc], H1[45], k1[64];
    int c = blockIdx.x, t = threadIdx.x;
    if (t < Cc) p1c[t] = pwk1[t*Cc + c];
    if (t >= 64 && t < 128) k1[t - 64] = dwk1[c*64 + (t - 64)];
    __syncthreads();
    if (t < 45) {
        float acc = 0.f;
        for (int e = 0; e < Cc; ++e) acc += p1c[e] * Gin[e*45 + t];
        H1[t] = acc;
    }
    __syncthreads();
    if (t < HTAPS) {
        float acc = 0.f;
        int s0 = t - 63; if (s0 < 0) s0 = 0;
        int s1 = t; if (s1 > 44) s1 = 44;
        for (int s = s0; s <= s1; ++s) acc += H1[s] * k1[t - s];
        Heff[c*HTAPS + t] = acc;
    }
}

// ---------------- K6a3: bias constant C ----------------
__global__ __launch_bounds__(64) void k_cc(const float* __restrict__ pwk1, const float* __restrict__ pwb1,
                                           const float* __restrict__ dwb1,
                                           const float* __restrict__ dwk2, const float* __restrict__ dwb2,
                                           const float* __restrict__ pwk2, const float* __restrict__ pwb2,
                                           const float* __restrict__ dwk3, const float* __restrict__ dwb3,
                                           const float* __restrict__ pwk3, const float* __restrict__ pwb3,
                                           float* __restrict__ Ccst)
{
    __shared__ float db1[Cc], cA[Cc], cB[Cc];
    int t = threadIdx.x;
    if (t < Cc) db1[t] = dwb1[t];
    __syncthreads();
    if (t < Cc) {
        float acc = pwb1[t];
        for (int c = 0; c < Cc; ++c) acc += pwk1[t*Cc + c] * db1[c];
        float sk = 0.f;
        for (int a = 0; a < 32; ++a) sk += dwk2[t*32 + a];
        cA[t] = acc * sk + dwb2[t];
    }
    __syncthreads();
    if (t < Cc) {
        float acc = pwb2[t];
        for (int e = 0; e < Cc; ++e) acc += pwk2[t*Cc + e] * cA[e];
        float sk = 0.f;
        for (int tt = 0; tt < 14; ++tt) sk += dwk3[t*14 + tt];
        cB[t] = acc * sk + dwb3[t];
    }
    __syncthreads();
    float v = (t < Cc) ? pwk3[61*Cc + t] * cB[t] : 0.f;
    for (int off = 32; off; off >>= 1) v += __shfl_down(v, off);
    if (t == 0) Ccst[0] = v + pwb3[61];
}

// ---------------- K6c: MFMA GEMM  P[ks][1920][62] = X[.,kslice] * H(kslice,.)  (bf16 inputs) ----------------
// A frag (16x32): lane l holds A[l&15][(l>>4)*8 + i].  B frag: B[(l>>4)*8+i][l&15].
// D (16x16): lane l holds D[(l>>4)*4 + i][l&15].   [m89/m91-verified family]
__global__ __launch_bounds__(256) void k_gemm(const float* __restrict__ x,
                                              const float* __restrict__ Heff,
                                              float* __restrict__ P)
{
    __shared__ __align__(16) unsigned short Xs[64*64];   // [row][k] bf16, XOR-swizzled
    __shared__ __align__(16) unsigned short Hs[64*64];   // [col][k] bf16, XOR-swizzled
    const int tid = threadIdx.x;
    const int mt = blockIdx.x % 30;
    const int ks = blockIdx.x / 30;
    const int k0 = ks * KSLICE;
    const int kend = (k0 + KSLICE < CL) ? (k0 + KSLICE) : CL;
    const int m0g = mt * 64;
    const int w = tid >> 6, l = tid & 63;
    const int arow = w*16 + (l & 15);
    const int klane = (l >> 4) * 8;
    const int sr = tid >> 2, sq4 = (tid & 3) << 4;

    f32x4 acc[4];
#pragma unroll
    for (int ct = 0; ct < 4; ++ct) acc[ct] = (f32x4){0.f, 0.f, 0.f, 0.f};

    for (int kb = k0; kb < kend; kb += 64) {
        // ---- stage X tile (64 rows x 64 k) as bf16, swizzled ----
        {
            const float* xp = x + (size_t)(m0g + sr)*CL + kb + sq4;
            unsigned short tb[16];
            if (kb + 64 <= kend) {
#pragma unroll
                for (int t2 = 0; t2 < 8; ++t2) {
                    float2 v = *reinterpret_cast<const float2*>(xp + 2*t2);
                    tb[2*t2]   = f2bf(v.x);
                    tb[2*t2+1] = f2bf(v.y);
                }
            } else {
#pragma unroll
                for (int t = 0; t < 16; ++t) {
                    int col = kb + sq4 + t;
                    tb[t] = f2bf((col < kend) ? xp[t] : 0.f);
                }
            }
            int i0 = (sr*64 + sq4)     ^ ((sr & 7) << 3);
            int i1 = (sr*64 + sq4 + 8) ^ ((sr & 7) << 3);
            short8 p0, p1;
#pragma unroll
            for (int t = 0; t < 8; ++t) { p0[t] = (short)tb[t]; p1[t] = (short)tb[t+8]; }
            *reinterpret_cast<short8*>(&Xs[i0]) = p0;
            *reinterpret_cast<short8*>(&Xs[i1]) = p1;
        }
        // ---- stage H tile: Hs[j][k] = Heff[c][l-j], c=kg/169 ----
        {
            int j = sr;
            unsigned short tb[16];
#pragma unroll
            for (int t = 0; t < 16; ++t) {
                int kg = kb + sq4 + t;
                float hv = 0.f;
                if (kg < kend && j < Cc) {
                    int c = kg / Ll, ll = kg - c*Ll;
                    int a = ll - j;
                    if (a >= 0 && a < HTAPS) hv = Heff[c*HTAPS + a];
                }
                tb[t] = f2bf(hv);
            }
            int i0 = (j*64 + sq4)     ^ ((j & 7) << 3);
            int i1 = (j*64 + sq4 + 8) ^ ((j & 7) << 3);
            short8 p0, p1;
#pragma unroll
            for (int t = 0; t < 8; ++t) { p0[t] = (short)tb[t]; p1[t] = (short)tb[t+8]; }
            *reinterpret_cast<short8*>(&Hs[i0]) = p0;
            *reinterpret_cast<short8*>(&Hs[i1]) = p1;
        }
        __syncthreads();
        // ---- MFMA: 2 k-steps of 32, 4 col-tiles ----
#pragma unroll
        for (int ks2 = 0; ks2 < 2; ++ks2) {
            int kk0 = ks2*32 + klane;
            int ia = (arow*64 + kk0) ^ ((arow & 7) << 3);
            short8 af = *reinterpret_cast<const short8*>(&Xs[ia]);
#pragma unroll
            for (int ct = 0; ct < 4; ++ct) {
                int bcol = ct*16 + (l & 15);
                int ib = (bcol*64 + kk0) ^ ((bcol & 7) << 3);
                short8 bf = *reinterpret_cast<const short8*>(&Hs[ib]);
                acc[ct] = __builtin_amdgcn_mfma_f32_16x16x32_bf16(af, bf, acc[ct], 0, 0, 0);
            }
        }
        __syncthreads();
    }
#pragma unroll
    for (int ct = 0; ct < 4; ++ct) {
        int col = ct*16 + (l & 15);
        if (col < Cc) {
#pragma unroll
            for (int i = 0; i < 4; ++i) {
                int row = m0g + w*16 + (l >> 4)*4 + i;
                P[(size_t)(ks*1920 + row)*Cc + col] = acc[ct][i];
            }
        }
    }
}

// ---------------- K6d: reduce partials -> d61[m][j] (m = b*30+t) ----------------
__global__ __launch_bounds__(256) void k_dred(const float* __restrict__ P,
                                              const float* __restrict__ Cconst,
                                              float* __restrict__ d61)
{
    int idx = blockIdx.x * 256 + threadIdx.x;
    if (idx >= 1920 * Cc) return;
    float a = Cconst[0];
#pragma unroll
    for (int ks = 0; ks < KSPLIT; ++ks) a += P[(size_t)ks * (1920*Cc) + idx];
    d61[idx] = a;
}

// ---------------- K7: adj_t row, v, g, pre-gates per (b,t) ----------------
__global__ __launch_bounds__(256) void k_g(const float* __restrict__ x, const float* __restrict__ d61,
    const float* __restrict__ adjr, const float* __restrict__ gcn_w, const float* __restrict__ gcn_b,
    const float* __restrict__ w_r, const float* __restrict__ w_u, const float* __restrict__ w_c,
    float* __restrict__ preR, float* __restrict__ preU, float* __restrict__ preC)
{
    __shared__ float adjt[Cc];
    __shared__ float v[Ll];
    __shared__ float g[GRU];
    int bt = blockIdx.x, t = bt >> 6, b = bt & 63;
    int m = b * Ss + t;
    int tid = threadIdx.x;
    if (tid < Cc) {
        float sv = d61[(size_t)m*Cc + tid] + adjr[b*Cc + tid];
        adjt[tid] = 1.f / (1.f + expf(-sv));
    }
    __syncthreads();
    if (tid < Ll) {
        const float* xp = x + (size_t)m*CL + tid;
        float acc = 0.f;
        for (int j = 0; j < Cc; ++j) acc += adjt[j] * xp[j*Ll];
        v[tid] = acc;
    }
    __syncthreads();
    if (tid < GRU) {
        float acc = gcn_b[tid];
        for (int l = 0; l < Ll; ++l) acc += v[l] * gcn_w[l*GRU + tid];
        g[tid] = acc;
    }
    __syncthreads();
    if (tid < GRU) {
        float ar = 0.f, au = 0.f, ac = 0.f;
        for (int i = 0; i < GRU; ++i) {
            float gi = g[i];
            ar += gi * w_r[i*GRU + tid];
            au += gi * w_u[i*GRU + tid];
            ac += gi * w_c[i*GRU + tid];
        }
        preR[(size_t)bt*GRU + tid] = ar;
        preU[(size_t)bt*GRU + tid] = au;
        preC[(size_t)bt*GRU + tid] = ac;
    }
}

// ---------------- K8: GRU scan over t ----------------
__global__ __launch_bounds__(64) void k_gru(const float* __restrict__ preR, const float* __restrict__ preU,
    const float* __restrict__ preC,
    const float* __restrict__ w_r, const float* __restrict__ wb_r,
    const float* __restrict__ w_u, const float* __restrict__ wb_u,
    const float* __restrict__ w_c, const float* __restrict__ wb_c,
    const float* __restrict__ b_r, const float* __restrict__ b_u, const float* __restrict__ b_c,
    float* __restrict__ out)
{
    __shared__ float W2r[GRU*GRU], W2u[GRU*GRU], W2c[GRU*GRU];
    __shared__ float h[GRU], rh[GRU];
    int b = blockIdx.x, o = threadIdx.x;
    for (int i = 0; i < GRU; ++i) {
        W2r[i*GRU + o] = w_r[(GRU + i)*GRU + o];
        W2u[i*GRU + o] = w_u[(GRU + i)*GRU + o];
        W2c[i*GRU + o] = w_c[(GRU + i)*GRU + o];
    }
    float cr = wb_r[o] + b_r[o];
    float cu = wb_u[o] + b_u[o];
    float cc = wb_c[o] + b_c[o];
    float hreg = 0.f;
    h[o] = 0.f;
    __syncthreads();
    for (int t = 0; t < Ss; ++t) {
        size_t base = (size_t)(t*Bb + b)*GRU + o;
        float ar = preR[base] + cr;
        float au = preU[base] + cu;
        for (int i = 0; i < GRU; ++i) {
            float hi = h[i];
            ar += hi * W2r[i*GRU + o];
            au += hi * W2u[i*GRU + o];
        }
        float r = 1.f / (1.f + expf(-ar));
        float u = 1.f / (1.f + expf(-au));
        rh[o] = r * hreg;
        __syncthreads();
        float ac = preC[base] + cc;
        for (int i = 0; i < GRU; ++i) ac += rh[i] * W2c[i*GRU + o];
        float ct = tanhf(ac);
        hreg = u * hreg + (1.f - u) * ct;
        __syncthreads();
        h[o] = hreg;
        __syncthreads();
    }
    out[b*GRU + o] = hreg;
}

// ---------------- launcher ----------------
extern "C" void kernel_launch(void* const* d_in, const int* in_sizes, int n_in,
                              void* d_out, int out_size, void* d_ws, size_t ws_size,
                              hipStream_t stream)
{
    const float* x     = (const float*)d_in[0];
    const float* se_w1 = (const float*)d_in[1];
    const float* se_w2 = (const float*)d_in[2];
    const float* dwk1  = (const float*)d_in[3];
    const float* dwb1  = (const float*)d_in[4];
    const float* pwk1  = (const float*)d_in[5];
    const float* pwb1  = (const float*)d_in[6];
    const float* dwk2  = (const float*)d_in[7];
    const float* dwb2  = (const float*)d_in[8];
    const float* pwk2  = (const float*)d_in[9];
    const float* pwb2  = (const float*)d_in[10];
    const float* dwk3  = (const float*)d_in[11];
    const float* dwb3  = (const float*)d_in[12];
    const float* pwk3  = (const float*)d_in[13];
    const float* pwb3  = (const float*)d_in[14];
    const float* gcn_w = (const float*)d_in[15];
    const float* gcn_b = (const float*)d_in[16];
    const float* w_r   = (const float*)d_in[17];
    const float* wb_r  = (const float*)d_in[18];
    const float* w_u   = (const float*)d_in[19];
    const float* wb_u  = (const float*)d_in[20];
    const float* w_c   = (const float*)d_in[21];
    const float* wb_c  = (const float*)d_in[22];
    const float* b_r   = (const float*)d_in[23];
    const float* b_u   = (const float*)d_in[24];
    const float* b_c   = (const float*)d_in[25];
    float* out = (float*)d_out;

    // workspace (floats). msb/f_re/f_im region (3x670592 = 2,011,776) is dead
    // after k_dftg/k_adjrow; P (16*119040 = 1,904,640) aliases it.
    // T (169*344 = 58,136) aliases preR (dead until k_g).
    float* ws   = (float*)d_ws;
    float* sq   = ws;                    // 1920
    float* aw   = sq   + 1920;           // 1920
    float* msb  = aw   + 1920;           // 670592
    float* f_re = msb  + 670592;         // 670592
    float* f_im = f_re + 670592;         // 670592
    float* adjr = f_im + 670592;         // 3968
    float* d61  = adjr + 3968;           // 119040
    float* preR = d61  + 119040;         // 122880
    float* preU = preR + 122880;         // 122880
    float* preC = preU + 122880;         // 122880
    float* Heff = preC + 122880;         // 6696
    float* Ccst = Heff + 6696;           // 8
    float* Gbuf = Ccst + 8;              // 2790
    float* P    = msb;                   // alias
    float* Twd  = preR;                  // alias (58,136 <= 368,640)

    k_sq<<<Bb*Ss, 256, 0, stream>>>(x, sq);
    k_se<<<1, 64, 0, stream>>>(sq, se_w1, se_w2, aw);
    k_maxseg<<<(Bb*CL + 255)/256, 256, 0, stream>>>(x, aw, msb);
    k_tw<<<(Ll*TS + 255)/256, 256, 0, stream>>>(Twd);
    k_dftg<<<62*6, 256, 0, stream>>>(msb, Twd, f_re, f_im);
    k_adjrow<<<Bb*Cc, 64, 0, stream>>>(f_re, f_im, adjr);
    k_fg<<<Cc, 64, 0, stream>>>(pwk2, pwk3, dwk2, dwk3, Gbuf);
    k_h1h<<<Cc, 128, 0, stream>>>(pwk1, dwk1, Gbuf, Heff);
    k_cc<<<1, 64, 0, stream>>>(pwk1, pwb1, dwb1, dwk2, dwb2, pwk2, pwb2,
                               dwk3, dwb3, pwk3, pwb3, Ccst);
    k_gemm<<<30*KSPLIT, 256, 0, stream>>>(x, Heff, P);
    k_dred<<<(1920*Cc + 255)/256, 256, 0, stream>>>(P, Ccst, d61);
    k_g<<<Ss*Bb, 256, 0, stream>>>(x, d61, adjr, gcn_w, gcn_b, w_r, w_u, w_c, preR, preU, preC);
    k_gru<<<Bb, 64, 0, stream>>>(preR, preU, preC, w_r, wb_r, w_u, wb_u, w_c, wb_c,
                                 b_r, b_u, b_c, out);
}

// Round 8
// 153.485 us; speedup vs baseline: 14.0283x; 1.3445x over previous
//
#include <hip/hip_runtime.h>
#include <hip/hip_bf16.h>
#include <math.h>

#define Bb 64
#define Ss 30
#define Cc 62
#define Ll 169
#define CL (Cc*Ll)          // 10478
#define GRU 64
#define HTAPS 108           // 64+32+14-2
#define KSPLIT 16
#define KSLICE 656          // 16*656 >= 10478
#define MSS 170             // ms row stride (even, for aligned float2)

typedef __attribute__((ext_vector_type(8))) short short8;
typedef __attribute__((ext_vector_type(4))) float f32x4;

__device__ __forceinline__ unsigned short f2bf(float f)
{
    union { float f; unsigned int u; } v; v.f = f;
    unsigned int u = v.u + 0x7fffu + ((v.u >> 16) & 1u);   // RNE
    return (unsigned short)(u >> 16);
}

// ---------------- K1: sq[b,s] = mean over (c,L) ----------------
__global__ __launch_bounds__(256) void k_sq(const float* __restrict__ x, float* __restrict__ sq)
{
    __shared__ float red[4];
    int bs = blockIdx.x;
    const float* p = x + (size_t)bs * CL;
    float acc = 0.f;
    for (int i = threadIdx.x; i < CL; i += 256) acc += p[i];
    for (int off = 32; off; off >>= 1) acc += __shfl_down(acc, off);
    if ((threadIdx.x & 63) == 0) red[threadIdx.x >> 6] = acc;
    __syncthreads();
    if (threadIdx.x == 0) sq[bs] = (red[0] + red[1] + red[2] + red[3]) / (float)CL;
}

// ---------------- K2: SE MLP -> a[b,s] ----------------
__global__ __launch_bounds__(64) void k_se(const float* __restrict__ sq, const float* __restrict__ w1,
                                           const float* __restrict__ w2, float* __restrict__ aout)
{
    int b = threadIdx.x;
    float hid[15];
#pragma unroll
    for (int j = 0; j < 15; ++j) {
        float h = 0.f;
        for (int s = 0; s < Ss; ++s) h += sq[b*Ss + s] * w1[s*15 + j];
        hid[j] = fmaxf(h, 0.f);
    }
    for (int s = 0; s < Ss; ++s) {
        float o = 0.f;
#pragma unroll
        for (int j = 0; j < 15; ++j) o += hid[j] * w2[j*Ss + s];
        aout[b*Ss + s] = 1.f / (1.f + expf(-o));
    }
}

// ---------------- K3: max_seg rows (stride 170) ----------------
__global__ __launch_bounds__(256) void k_maxseg(const float* __restrict__ x, const float* __restrict__ a,
                                                float* __restrict__ ms)
{
    int idx = blockIdx.x * 256 + threadIdx.x;
    if (idx >= Bb*CL) return;
    int row = idx / Ll;                 // b*62 + c
    int l   = idx - row*Ll;
    int b   = row / Cc;
    int c   = row - b*Cc;
    float m = -INFINITY;
    for (int s = 0; s < Ss; ++s) {
        float v = x[(size_t)(b*Ss + s)*CL + c*Ll + l] * a[b*Ss + s];
        m = fmaxf(m, v);
    }
    ms[(size_t)row*MSS + l] = m;
}

// ---------------- K4a: transposed bf16 twiddle TBt[384][192] ----------------
// TBt[col][n] = col<169 ? cos(2pi n col/169) : (col<338 ? -sin(2pi n (col-169)/169) : 0)
__global__ __launch_bounds__(256) void k_tw(unsigned short* __restrict__ T)
{
    int idx = blockIdx.x * 256 + threadIdx.x;
    if (idx >= 384*192) return;
    int col = idx / 192, n = idx - col*192;
    float v = 0.f;
    if (col < 338 && n < Ll) {
        int kp = (col < Ll) ? col : col - Ll;
        int m = (n * kp) % Ll;
        float ang = 6.28318530717958647692f * (float)m / (float)Ll;
        v = (col < Ll) ? cosf(ang) : -sinf(ang);
    }
    T[idx] = f2bf(v);
}

// ---------------- K4b: DFT as MFMA GEMM  F[3968][338] = ms * T ----------------
__global__ __launch_bounds__(256) void k_dftg(const float* __restrict__ ms,
                                              const unsigned short* __restrict__ T,
                                              float* __restrict__ fre, float* __restrict__ fim)
{
    __shared__ __align__(16) unsigned short As[64*64];
    __shared__ __align__(16) unsigned short Bs[64*64];
    const int tid = threadIdx.x;
    const int mtile = blockIdx.x % 62;
    const int ntile = blockIdx.x / 62;             // 0..5
    const int m0 = mtile*64, n0g = ntile*64;
    const int w = tid >> 6, l = tid & 63;
    const int arow = w*16 + (l & 15);
    const int klane = (l >> 4) * 8;
    const int sr = tid >> 2, sq4 = (tid & 3) << 4;

    f32x4 acc[4];
#pragma unroll
    for (int ct = 0; ct < 4; ++ct) acc[ct] = (f32x4){0.f, 0.f, 0.f, 0.f};

    for (int kb = 0; kb < 192; kb += 64) {
        // ---- stage A (ms rows, bf16, swizzled) ----
        {
            const float* ap = ms + (size_t)(m0 + sr)*MSS + kb + sq4;
            unsigned short tb[16];
            if (kb + 64 <= Ll) {
#pragma unroll
                for (int t2 = 0; t2 < 8; ++t2) {
                    float2 v = *reinterpret_cast<const float2*>(ap + 2*t2);
                    tb[2*t2]   = f2bf(v.x);
                    tb[2*t2+1] = f2bf(v.y);
                }
            } else {
#pragma unroll
                for (int t = 0; t < 16; ++t) {
                    int col = kb + sq4 + t;
                    tb[t] = (col < Ll) ? f2bf(ap[t]) : (unsigned short)0;
                }
            }
            int i0 = (sr*64 + sq4)     ^ ((sr & 7) << 3);
            int i1 = (sr*64 + sq4 + 8) ^ ((sr & 7) << 3);
            short8 p0, p1;
#pragma unroll
            for (int t = 0; t < 8; ++t) { p0[t] = (short)tb[t]; p1[t] = (short)tb[t+8]; }
            *reinterpret_cast<short8*>(&As[i0]) = p0;
            *reinterpret_cast<short8*>(&As[i1]) = p1;
        }
        // ---- stage B (TBt rows = output cols, already bf16, swizzled) ----
        {
            const unsigned short* tp = T + (size_t)(n0g + sr)*192 + kb + sq4;
            short8 p0 = *reinterpret_cast<const short8*>(tp);
            short8 p1 = *reinterpret_cast<const short8*>(tp + 8);
            int i0 = (sr*64 + sq4)     ^ ((sr & 7) << 3);
            int i1 = (sr*64 + sq4 + 8) ^ ((sr & 7) << 3);
            *reinterpret_cast<short8*>(&Bs[i0]) = p0;
            *reinterpret_cast<short8*>(&Bs[i1]) = p1;
        }
        __syncthreads();
#pragma unroll
        for (int ks2 = 0; ks2 < 2; ++ks2) {
            int kk0 = ks2*32 + klane;
            int ia = (arow*64 + kk0) ^ ((arow & 7) << 3);
            short8 af = *reinterpret_cast<const short8*>(&As[ia]);
#pragma unroll
            for (int ct = 0; ct < 4; ++ct) {
                int bcol = ct*16 + (l & 15);
                int ib = (bcol*64 + kk0) ^ ((bcol & 7) << 3);
                short8 bf = *reinterpret_cast<const short8*>(&Bs[ib]);
                acc[ct] = __builtin_amdgcn_mfma_f32_16x16x32_bf16(af, bf, acc[ct], 0, 0, 0);
            }
        }
        __syncthreads();
    }
#pragma unroll
    for (int ct = 0; ct < 4; ++ct) {
        int col = n0g + ct*16 + (l & 15);
#pragma unroll
        for (int i = 0; i < 4; ++i) {
            int row = m0 + w*16 + (l >> 4)*4 + i;
            if (col < Ll)       fre[(size_t)row*Ll + col] = acc[ct][i];
            else if (col < 338) fim[(size_t)row*Ll + (col - Ll)] = acc[ct][i];
        }
    }
}

// ---------------- K5: adj row 61 ----------------
__global__ __launch_bounds__(64) void k_adjrow(const float* __restrict__ fre, const float* __restrict__ fim,
                                               float* __restrict__ adjr)
{
    int b = blockIdx.x / Cc;
    int j = blockIdx.x % Cc;
    int lane = threadIdx.x;
    const float* re61 = fre + (size_t)(b*Cc + 61)*Ll;
    const float* im61 = fim + (size_t)(b*Cc + 61)*Ll;
    const float* rej  = fre + (size_t)(b*Cc + j)*Ll;
    const float* imj  = fim + (size_t)(b*Cc + j)*Ll;
    float num = 0.f, den = 0.f;
    for (int l = lane; l < Ll; l += 64) {
        float ar = re61[l], ai = im61[l];
        float br = rej[l],  bi = imj[l];
        num += ai*br - ar*bi;
        den += sqrtf(ar*ar + ai*ai) * sqrtf(br*br + bi*bi);
    }
    for (int off = 32; off; off >>= 1) { num += __shfl_down(num, off); den += __shfl_down(den, off); }
    if (lane == 0) adjr[b*Cc + j] = (j == 61) ? 0.f : num / den;
}

// ---------------- K6a1: per-e F then G (62 blocks) ----------------
__global__ __launch_bounds__(64) void k_fg(const float* __restrict__ pwk2, const float* __restrict__ pwk3,
                                           const float* __restrict__ dwk2, const float* __restrict__ dwk3,
                                           float* __restrict__ Gout)
{
    __shared__ float q[Cc], p2c[Cc], F[14], k2[32];
    int e = blockIdx.x, t = threadIdx.x;
    if (t < Cc) { q[t] = pwk3[61*Cc + t]; p2c[t] = pwk2[t*Cc + e]; }
    if (t < 32) k2[t] = dwk2[e*32 + t];
    __syncthreads();
    if (t < 14) {
        float acc = 0.f;
        for (int f = 0; f < Cc; ++f) acc += q[f] * p2c[f] * dwk3[f*14 + t];
        F[t] = acc;
    }
    __syncthreads();
    if (t < 45) {
        float acc = 0.f;
        int t0 = t - 31; if (t0 < 0) t0 = 0;
        int t1 = t; if (t1 > 13) t1 = 13;
        for (int tt = t0; tt <= t1; ++tt) acc += F[tt] * k2[t - tt];
        Gout[e*45 + t] = acc;
    }
}

// ---------------- K6a2: per-c H1 then Heff (62 blocks) ----------------
__global__ __launch_bounds__(128) void k_h1h(const float* __restrict__ pwk1, const float* __restrict__ dwk1,
                                             const float* __restrict__ Gin, float* __restrict__ Heff)
{
    __shared__ float p1c[Cc], H1[45], k1[64];
    int c = blockIdx.x, t = threadIdx.x;
    if (t < Cc) p1c[t] = pwk1[t*Cc + c];
    if (t >= 64 && t < 128) k1[t - 64] = dwk1[c*64 + (t - 64)];
    __syncthreads();
    if (t < 45) {
        float acc = 0.f;
        for (int e = 0; e < Cc; ++e) acc += p1c[e] * Gin[e*45 + t];
        H1[t] = acc;
    }
    __syncthreads();
    if (t < HTAPS) {
        float acc = 0.f;
        int s0 = t - 63; if (s0 < 0) s0 = 0;
        int s1 = t; if (s1 > 44) s1 = 44;
        for (int s = s0; s <= s1; ++s) acc += H1[s] * k1[t - s];
        Heff[c*HTAPS + t] = acc;
    }
}

// ---------------- K6a3: bias constant C ----------------
__global__ __launch_bounds__(64) void k_cc(const float* __restrict__ pwk1, const float* __restrict__ pwb1,
                                           const float* __restrict__ dwb1,
                                           const float* __restrict__ dwk2, const float* __restrict__ dwb2,
                                           const float* __restrict__ pwk2, const float* __restrict__ pwb2,
                                           const float* __restrict__ dwk3, const float* __restrict__ dwb3,
                                           const float* __restrict__ pwk3, const float* __restrict__ pwb3,
                                           float* __restrict__ Ccst)
{
    __shared__ float db1[Cc], cA[Cc], cB[Cc];
    int t = threadIdx.x;
    if (t < Cc) db1[t] = dwb1[t];
    __syncthreads();
    if (t < Cc) {
        float acc = pwb1[t];
        for (int c = 0; c < Cc; ++c) acc += pwk1[t*Cc + c] * db1[c];
        float sk = 0.f;
        for (int a = 0; a < 32; ++a) sk += dwk2[t*32 + a];
        cA[t] = acc * sk + dwb2[t];
    }
    __syncthreads();
    if (t < Cc) {
        float acc = pwb2[t];
        for (int e = 0; e < Cc; ++e) acc += pwk2[t*Cc + e] * cA[e];
        float sk = 0.f;
        for (int tt = 0; tt < 14; ++tt) sk += dwk3[t*14 + tt];
        cB[t] = acc * sk + dwb3[t];
    }
    __syncthreads();
    float v = (t < Cc) ? pwk3[61*Cc + t] * cB[t] : 0.f;
    for (int off = 32; off; off >>= 1) v += __shfl_down(v, off);
    if (t == 0) Ccst[0] = v + pwb3[61];
}

// ---------------- K6c: MFMA GEMM  P[ks][1920][62] = X * H  (bf16) ----------------
__global__ __launch_bounds__(256) void k_gemm(const float* __restrict__ x,
                                              const float* __restrict__ Heff,
                                              float* __restrict__ P)
{
    __shared__ __align__(16) unsigned short Xs[64*64];
    __shared__ __align__(16) unsigned short Hs[64*64];
    const int tid = threadIdx.x;
    const int mt = blockIdx.x % 30;
    const int ks = blockIdx.x / 30;
    const int k0 = ks * KSLICE;
    const int kend = (k0 + KSLICE < CL) ? (k0 + KSLICE) : CL;
    const int m0g = mt * 64;
    const int w = tid >> 6, l = tid & 63;
    const int arow = w*16 + (l & 15);
    const int klane = (l >> 4) * 8;
    const int sr = tid >> 2, sq4 = (tid & 3) << 4;

    f32x4 acc[4];
#pragma unroll
    for (int ct = 0; ct < 4; ++ct) acc[ct] = (f32x4){0.f, 0.f, 0.f, 0.f};

    for (int kb = k0; kb < kend; kb += 64) {
        {
            const float* xp = x + (size_t)(m0g + sr)*CL + kb + sq4;
            unsigned short tb[16];
            if (kb + 64 <= kend) {
#pragma unroll
                for (int t2 = 0; t2 < 8; ++t2) {
                    float2 v = *reinterpret_cast<const float2*>(xp + 2*t2);
                    tb[2*t2]   = f2bf(v.x);
                    tb[2*t2+1] = f2bf(v.y);
                }
            } else {
#pragma unroll
                for (int t = 0; t < 16; ++t) {
                    int col = kb + sq4 + t;
                    tb[t] = f2bf((col < kend) ? xp[t] : 0.f);
                }
            }
            int i0 = (sr*64 + sq4)     ^ ((sr & 7) << 3);
            int i1 = (sr*64 + sq4 + 8) ^ ((sr & 7) << 3);
            short8 p0, p1;
#pragma unroll
            for (int t = 0; t < 8; ++t) { p0[t] = (short)tb[t]; p1[t] = (short)tb[t+8]; }
            *reinterpret_cast<short8*>(&Xs[i0]) = p0;
            *reinterpret_cast<short8*>(&Xs[i1]) = p1;
        }
        {
            int j = sr;
            unsigned short tb[16];
#pragma unroll
            for (int t = 0; t < 16; ++t) {
                int kg = kb + sq4 + t;
                float hv = 0.f;
                if (kg < kend && j < Cc) {
                    int c = kg / Ll, ll = kg - c*Ll;
                    int a = ll - j;
                    if (a >= 0 && a < HTAPS) hv = Heff[c*HTAPS + a];
                }
                tb[t] = f2bf(hv);
            }
            int i0 = (j*64 + sq4)     ^ ((j & 7) << 3);
            int i1 = (j*64 + sq4 + 8) ^ ((j & 7) << 3);
            short8 p0, p1;
#pragma unroll
            for (int t = 0; t < 8; ++t) { p0[t] = (short)tb[t]; p1[t] = (short)tb[t+8]; }
            *reinterpret_cast<short8*>(&Hs[i0]) = p0;
            *reinterpret_cast<short8*>(&Hs[i1]) = p1;
        }
        __syncthreads();
#pragma unroll
        for (int ks2 = 0; ks2 < 2; ++ks2) {
            int kk0 = ks2*32 + klane;
            int ia = (arow*64 + kk0) ^ ((arow & 7) << 3);
            short8 af = *reinterpret_cast<const short8*>(&Xs[ia]);
#pragma unroll
            for (int ct = 0; ct < 4; ++ct) {
                int bcol = ct*16 + (l & 15);
                int ib = (bcol*64 + kk0) ^ ((bcol & 7) << 3);
                short8 bf = *reinterpret_cast<const short8*>(&Hs[ib]);
                acc[ct] = __builtin_amdgcn_mfma_f32_16x16x32_bf16(af, bf, acc[ct], 0, 0, 0);
            }
        }
        __syncthreads();
    }
#pragma unroll
    for (int ct = 0; ct < 4; ++ct) {
        int col = ct*16 + (l & 15);
        if (col < Cc) {
#pragma unroll
            for (int i = 0; i < 4; ++i) {
                int row = m0g + w*16 + (l >> 4)*4 + i;
                P[(size_t)(ks*1920 + row)*Cc + col] = acc[ct][i];
            }
        }
    }
}

// ---------------- K6d: reduce partials -> d61 ----------------
__global__ __launch_bounds__(256) void k_dred(const float* __restrict__ P,
                                              const float* __restrict__ Cconst,
                                              float* __restrict__ d61)
{
    int idx = blockIdx.x * 256 + threadIdx.x;
    if (idx >= 1920 * Cc) return;
    float a = Cconst[0];
#pragma unroll
    for (int ks = 0; ks < KSPLIT; ++ks) a += P[(size_t)ks * (1920*Cc) + idx];
    d61[idx] = a;
}

// ---------------- K7: adj_t row, v, g, pre-gates per (b,t) ----------------
__global__ __launch_bounds__(256) void k_g(const float* __restrict__ x, const float* __restrict__ d61,
    const float* __restrict__ adjr, const float* __restrict__ gcn_w, const float* __restrict__ gcn_b,
    const float* __restrict__ w_r, const float* __restrict__ w_u, const float* __restrict__ w_c,
    float* __restrict__ preR, float* __restrict__ preU, float* __restrict__ preC)
{
    __shared__ float adjt[Cc];
    __shared__ float v[Ll];
    __shared__ float g[GRU];
    int bt = blockIdx.x, t = bt >> 6, b = bt & 63;
    int m = b * Ss + t;
    int tid = threadIdx.x;
    if (tid < Cc) {
        float sv = d61[(size_t)m*Cc + tid] + adjr[b*Cc + tid];
        adjt[tid] = 1.f / (1.f + expf(-sv));
    }
    __syncthreads();
    if (tid < Ll) {
        const float* xp = x + (size_t)m*CL + tid;
        float acc = 0.f;
        for (int j = 0; j < Cc; ++j) acc += adjt[j] * xp[j*Ll];
        v[tid] = acc;
    }
    __syncthreads();
    if (tid < GRU) {
        float acc = gcn_b[tid];
        for (int l = 0; l < Ll; ++l) acc += v[l] * gcn_w[l*GRU + tid];
        g[tid] = acc;
    }
    __syncthreads();
    if (tid < GRU) {
        float ar = 0.f, au = 0.f, ac = 0.f;
        for (int i = 0; i < GRU; ++i) {
            float gi = g[i];
            ar += gi * w_r[i*GRU + tid];
            au += gi * w_u[i*GRU + tid];
            ac += gi * w_c[i*GRU + tid];
        }
        preR[(size_t)bt*GRU + tid] = ar;
        preU[(size_t)bt*GRU + tid] = au;
        preC[(size_t)bt*GRU + tid] = ac;
    }
}

// ---------------- K8: GRU scan, 4-wave cooperative ----------------
__global__ __launch_bounds__(256) void k_gru(const float* __restrict__ preR, const float* __restrict__ preU,
    const float* __restrict__ preC,
    const float* __restrict__ w_r, const float* __restrict__ wb_r,
    const float* __restrict__ w_u, const float* __restrict__ wb_u,
    const float* __restrict__ w_c, const float* __restrict__ wb_c,
    const float* __restrict__ b_r, const float* __restrict__ b_u, const float* __restrict__ b_c,
    float* __restrict__ out)
{
    __shared__ float h[GRU], rh[GRU];
    __shared__ float part[3][4][GRU];
    __shared__ float preS[Ss][3][GRU];      // 23 KB
    const int b = blockIdx.x;
    const int t = threadIdx.x, o = t & 63, q = t >> 6;

    float wr[16], wu[16], wc[16];
#pragma unroll
    for (int i = 0; i < 16; ++i) {
        wr[i] = w_r[(GRU + q*16 + i)*GRU + o];
        wu[i] = w_u[(GRU + q*16 + i)*GRU + o];
        wc[i] = w_c[(GRU + q*16 + i)*GRU + o];
    }
    for (int u = t; u < Ss*GRU; u += 256) {
        int s = u >> 6, oo = u & 63;
        size_t base = (size_t)(s*Bb + b)*GRU + oo;
        preS[s][0][oo] = preR[base];
        preS[s][1][oo] = preU[base];
        preS[s][2][oo] = preC[base];
    }
    const float cr = wb_r[o] + b_r[o];
    const float cu = wb_u[o] + b_u[o];
    const float cc = wb_c[o] + b_c[o];
    if (t < GRU) h[t] = 0.f;
    float ug = 0.f;
    __syncthreads();

    for (int s = 0; s < Ss; ++s) {
        float ar = 0.f, au = 0.f;
#pragma unroll
        for (int i = 0; i < 16; ++i) {
            float hi = h[q*16 + i];
            ar += hi * wr[i];
            au += hi * wu[i];
        }
        part[0][q][o] = ar;
        part[1][q][o] = au;
        __syncthreads();
        if (q == 0) {
            float arf = preS[s][0][o] + cr + part[0][0][o] + part[0][1][o] + part[0][2][o] + part[0][3][o];
            float auf = preS[s][1][o] + cu + part[1][0][o] + part[1][1][o] + part[1][2][o] + part[1][3][o];
            float r = 1.f / (1.f + expf(-arf));
            ug = 1.f / (1.f + expf(-auf));
            rh[o] = r * h[o];
        }
        __syncthreads();
        float ac = 0.f;
#pragma unroll
        for (int i = 0; i < 16; ++i) ac += rh[q*16 + i] * wc[i];
        part[2][q][o] = ac;
        __syncthreads();
        if (q == 0) {
            float acf = preS[s][2][o] + cc + part[2][0][o] + part[2][1][o] + part[2][2][o] + part[2][3][o];
            float ct = tanhf(acf);
            float hn = ug * h[o] + (1.f - ug) * ct;
            h[o] = hn;
            if (s == Ss - 1) out[b*GRU + o] = hn;
        }
        __syncthreads();
    }
}

// ---------------- launcher ----------------
extern "C" void kernel_launch(void* const* d_in, const int* in_sizes, int n_in,
                              void* d_out, int out_size, void* d_ws, size_t ws_size,
                              hipStream_t stream)
{
    const float* x     = (const float*)d_in[0];
    const float* se_w1 = (const float*)d_in[1];
    const float* se_w2 = (const float*)d_in[2];
    const float* dwk1  = (const float*)d_in[3];
    const float* dwb1  = (const float*)d_in[4];
    const float* pwk1  = (const float*)d_in[5];
    const float* pwb1  = (const float*)d_in[6];
    const float* dwk2  = (const float*)d_in[7];
    const float* dwb2  = (const float*)d_in[8];
    const float* pwk2  = (const float*)d_in[9];
    const float* pwb2  = (const float*)d_in[10];
    const float* dwk3  = (const float*)d_in[11];
    const float* dwb3  = (const float*)d_in[12];
    const float* pwk3  = (const float*)d_in[13];
    const float* pwb3  = (const float*)d_in[14];
    const float* gcn_w = (const float*)d_in[15];
    const float* gcn_b = (const float*)d_in[16];
    const float* w_r   = (const float*)d_in[17];
    const float* wb_r  = (const float*)d_in[18];
    const float* w_u   = (const float*)d_in[19];
    const float* wb_u  = (const float*)d_in[20];
    const float* w_c   = (const float*)d_in[21];
    const float* wb_c  = (const float*)d_in[22];
    const float* b_r   = (const float*)d_in[23];
    const float* b_u   = (const float*)d_in[24];
    const float* b_c   = (const float*)d_in[25];
    float* out = (float*)d_out;

    // workspace (floats). ms (stride 170) + f_re + f_im = 2,015,744 region is
    // dead after k_adjrow; P (16*119040 = 1,904,640) aliases it.
    // TBt (73,728 ushorts = 36,864 floats) aliases preR (dead until k_g).
    float* ws   = (float*)d_ws;
    float* sq   = ws;                    // 1920
    float* aw   = sq   + 1920;           // 1920
    float* msb  = aw   + 1920;           // 674560 (3968*170)
    float* f_re = msb  + 674560;         // 670592
    float* f_im = f_re + 670592;         // 670592
    float* adjr = f_im + 670592;         // 3968
    float* d61  = adjr + 3968;           // 119040
    float* preR = d61  + 119040;         // 122880
    float* preU = preR + 122880;         // 122880
    float* preC = preU + 122880;         // 122880
    float* Heff = preC + 122880;         // 6696
    float* Ccst = Heff + 6696;           // 8
    float* Gbuf = Ccst + 8;              // 2790
    float* P    = msb;                   // alias (1,904,640 <= 2,015,744)
    unsigned short* TBt = (unsigned short*)preR;  // alias (73,728 ushorts)

    k_sq<<<Bb*Ss, 256, 0, stream>>>(x, sq);
    k_se<<<1, 64, 0, stream>>>(sq, se_w1, se_w2, aw);
    k_maxseg<<<(Bb*CL + 255)/256, 256, 0, stream>>>(x, aw, msb);
    k_tw<<<(384*192 + 255)/256, 256, 0, stream>>>(TBt);
    k_dftg<<<62*6, 256, 0, stream>>>(msb, TBt, f_re, f_im);
    k_adjrow<<<Bb*Cc, 64, 0, stream>>>(f_re, f_im, adjr);
    k_fg<<<Cc, 64, 0, stream>>>(pwk2, pwk3, dwk2, dwk3, Gbuf);
    k_h1h<<<Cc, 128, 0, stream>>>(pwk1, dwk1, Gbuf, Heff);
    k_cc<<<1, 64, 0, stream>>>(pwk1, pwb1, dwb1, dwk2, dwb2, pwk2, pwb2,
                               dwk3, dwb3, pwk3, pwb3, Ccst);
    k_gemm<<<30*KSPLIT, 256, 0, stream>>>(x, Heff, P);
    k_dred<<<(1920*Cc + 255)/256, 256, 0, stream>>>(P, Ccst, d61);
    k_g<<<Ss*Bb, 256, 0, stream>>>(x, d61, adjr, gcn_w, gcn_b, w_r, w_u, w_c, preR, preU, preC);
    k_gru<<<Bb, 256, 0, stream>>>(preR, preU, preC, w_r, wb_r, w_u, wb_u, w_c, wb_c,
                                  b_r, b_u, b_c, out);
}

// Round 9
// 135.152 us; speedup vs baseline: 15.9313x; 1.1356x over previous
//
#include <hip/hip_runtime.h>
#include <hip/hip_bf16.h>
#include <math.h>

#define Bb 64
#define Ss 30
#define Cc 62
#define Ll 169
#define CL (Cc*Ll)          // 10478
#define GRU 64
#define HTAPS 108           // 64+32+14-2
#define KSPLIT 16
#define KSLICE 656          // 16*656 >= 10478
#define MSS 170             // ms row stride (even, for aligned float2)

typedef __attribute__((ext_vector_type(8))) short short8;
typedef __attribute__((ext_vector_type(4))) float f32x4;

__device__ __forceinline__ unsigned short f2bf(float f)
{
    union { float f; unsigned int u; } v; v.f = f;
    unsigned int u = v.u + 0x7fffu + ((v.u >> 16) & 1u);   // RNE
    return (unsigned short)(u >> 16);
}

// ---------------- K_misc: blk<62 -> fg(e=blk); blk==62 -> cc; blk>=63 -> twiddle ----------------
__global__ __launch_bounds__(256) void k_misc(
    const float* __restrict__ pwk1, const float* __restrict__ pwb1, const float* __restrict__ dwb1,
    const float* __restrict__ dwk2, const float* __restrict__ dwb2,
    const float* __restrict__ pwk2, const float* __restrict__ pwb2,
    const float* __restrict__ dwk3, const float* __restrict__ dwb3,
    const float* __restrict__ pwk3, const float* __restrict__ pwb3,
    float* __restrict__ Gout, float* __restrict__ Ccst, unsigned short* __restrict__ T)
{
    __shared__ float s0[Cc], s1[Cc], s2[Cc], F[14], k2[32];
    const int blk = blockIdx.x, t = threadIdx.x;
    if (blk < Cc) {
        // F[e][t] = sum_f pwk3[61,f]*pwk2[f,e]*dwk3[f,t];  G[e] = F conv dwk2[e]
        const int e = blk;
        if (t < Cc) { s0[t] = pwk3[61*Cc + t]; s1[t] = pwk2[t*Cc + e]; }
        if (t < 32) k2[t] = dwk2[e*32 + t];
        __syncthreads();
        if (t < 14) {
            float acc = 0.f;
            for (int f = 0; f < Cc; ++f) acc += s0[f] * s1[f] * dwk3[f*14 + t];
            F[t] = acc;
        }
        __syncthreads();
        if (t < 45) {
            float acc = 0.f;
            int t0 = t - 31; if (t0 < 0) t0 = 0;
            int t1 = t; if (t1 > 13) t1 = 13;
            for (int tt = t0; tt <= t1; ++tt) acc += F[tt] * k2[t - tt];
            Gout[e*45 + t] = acc;
        }
    } else if (blk == Cc) {
        // bias constant C
        if (t < Cc) s0[t] = dwb1[t];
        __syncthreads();
        if (t < Cc) {
            float acc = pwb1[t];
            for (int c = 0; c < Cc; ++c) acc += pwk1[t*Cc + c] * s0[c];
            float sk = 0.f;
            for (int a = 0; a < 32; ++a) sk += dwk2[t*32 + a];
            s1[t] = acc * sk + dwb2[t];
        }
        __syncthreads();
        if (t < Cc) {
            float acc = pwb2[t];
            for (int e = 0; e < Cc; ++e) acc += pwk2[t*Cc + e] * s1[e];
            float sk = 0.f;
            for (int tt = 0; tt < 14; ++tt) sk += dwk3[t*14 + tt];
            s2[t] = acc * sk + dwb3[t];
        }
        __syncthreads();
        if (t < 64) {
            float v = (t < Cc) ? pwk3[61*Cc + t] * s2[t] : 0.f;
            for (int off = 32; off; off >>= 1) v += __shfl_down(v, off);
            if (t == 0) Ccst[0] = v + pwb3[61];
        }
    } else {
        // transposed bf16 twiddle TBt[384][192]
        int idx = (blk - Cc - 1) * 256 + t;
        if (idx < 384*192) {
            int col = idx / 192, n = idx - col*192;
            float v = 0.f;
            if (col < 338 && n < Ll) {
                int kp = (col < Ll) ? col : col - Ll;
                int m = (n * kp) % Ll;
                float ang = 6.28318530717958647692f * (float)m / (float)Ll;
                v = (col < Ll) ? cosf(ang) : -sinf(ang);
            }
            T[idx] = f2bf(v);
        }
    }
}

// ---------------- K_h1h: per-c H1 then Heff (62 blocks) ----------------
__global__ __launch_bounds__(128) void k_h1h(const float* __restrict__ pwk1, const float* __restrict__ dwk1,
                                             const float* __restrict__ Gin, float* __restrict__ Heff)
{
    __shared__ float p1c[Cc], H1[45], k1[64];
    int c = blockIdx.x, t = threadIdx.x;
    if (t < Cc) p1c[t] = pwk1[t*Cc + c];
    if (t >= 64 && t < 128) k1[t - 64] = dwk1[c*64 + (t - 64)];
    __syncthreads();
    if (t < 45) {
        float acc = 0.f;
        for (int e = 0; e < Cc; ++e) acc += p1c[e] * Gin[e*45 + t];
        H1[t] = acc;
    }
    __syncthreads();
    if (t < HTAPS) {
        float acc = 0.f;
        int s0 = t - 63; if (s0 < 0) s0 = 0;
        int s1 = t; if (s1 > 44) s1 = 44;
        for (int s = s0; s <= s1; ++s) acc += H1[s] * k1[t - s];
        Heff[c*HTAPS + t] = acc;
    }
}

// ---------------- K_gemm: MFMA  P[ks][1920][62] = X*H (bf16)  +  row-sum partials Psq ----------------
__global__ __launch_bounds__(256) void k_gemm(const float* __restrict__ x,
                                              const float* __restrict__ Heff,
                                              float* __restrict__ P,
                                              float* __restrict__ Psq)
{
    __shared__ __align__(16) unsigned short Xs[64*64];
    __shared__ __align__(16) unsigned short Hs[64*64];
    __shared__ float Ps[256];
    const int tid = threadIdx.x;
    const int mt = blockIdx.x % 30;
    const int ks = blockIdx.x / 30;
    const int k0 = ks * KSLICE;
    const int kend = (k0 + KSLICE < CL) ? (k0 + KSLICE) : CL;
    const int m0g = mt * 64;
    const int w = tid >> 6, l = tid & 63;
    const int arow = w*16 + (l & 15);
    const int klane = (l >> 4) * 8;
    const int sr = tid >> 2, sq4 = (tid & 3) << 4;

    f32x4 acc[4];
#pragma unroll
    for (int ct = 0; ct < 4; ++ct) acc[ct] = (f32x4){0.f, 0.f, 0.f, 0.f};
    float psum = 0.f;

    for (int kb = k0; kb < kend; kb += 64) {
        {
            const float* xp = x + (size_t)(m0g + sr)*CL + kb + sq4;
            unsigned short tb[16];
            if (kb + 64 <= kend) {
#pragma unroll
                for (int t2 = 0; t2 < 8; ++t2) {
                    float2 v = *reinterpret_cast<const float2*>(xp + 2*t2);
                    psum += v.x + v.y;
                    tb[2*t2]   = f2bf(v.x);
                    tb[2*t2+1] = f2bf(v.y);
                }
            } else {
#pragma unroll
                for (int t = 0; t < 16; ++t) {
                    int col = kb + sq4 + t;
                    float vv = (col < kend) ? xp[t] : 0.f;
                    psum += vv;
                    tb[t] = f2bf(vv);
                }
            }
            int i0 = (sr*64 + sq4)     ^ ((sr & 7) << 3);
            int i1 = (sr*64 + sq4 + 8) ^ ((sr & 7) << 3);
            short8 p0, p1;
#pragma unroll
            for (int t = 0; t < 8; ++t) { p0[t] = (short)tb[t]; p1[t] = (short)tb[t+8]; }
            *reinterpret_cast<short8*>(&Xs[i0]) = p0;
            *reinterpret_cast<short8*>(&Xs[i1]) = p1;
        }
        {
            int j = sr;
            unsigned short tb[16];
#pragma unroll
            for (int t = 0; t < 16; ++t) {
                int kg = kb + sq4 + t;
                float hv = 0.f;
                if (kg < kend && j < Cc) {
                    int c = kg / Ll, ll = kg - c*Ll;
                    int a = ll - j;
                    if (a >= 0 && a < HTAPS) hv = Heff[c*HTAPS + a];
                }
                tb[t] = f2bf(hv);
            }
            int i0 = (j*64 + sq4)     ^ ((j & 7) << 3);
            int i1 = (j*64 + sq4 + 8) ^ ((j & 7) << 3);
            short8 p0, p1;
#pragma unroll
            for (int t = 0; t < 8; ++t) { p0[t] = (short)tb[t]; p1[t] = (short)tb[t+8]; }
            *reinterpret_cast<short8*>(&Hs[i0]) = p0;
            *reinterpret_cast<short8*>(&Hs[i1]) = p1;
        }
        __syncthreads();
#pragma unroll
        for (int ks2 = 0; ks2 < 2; ++ks2) {
            int kk0 = ks2*32 + klane;
            int ia = (arow*64 + kk0) ^ ((arow & 7) << 3);
            short8 af = *reinterpret_cast<const short8*>(&Xs[ia]);
#pragma unroll
            for (int ct = 0; ct < 4; ++ct) {
                int bcol = ct*16 + (l & 15);
                int ib = (bcol*64 + kk0) ^ ((bcol & 7) << 3);
                short8 bf = *reinterpret_cast<const short8*>(&Hs[ib]);
                acc[ct] = __builtin_amdgcn_mfma_f32_16x16x32_bf16(af, bf, acc[ct], 0, 0, 0);
            }
        }
        __syncthreads();
    }
    // row-sum partials (deterministic split-K)
    Ps[tid] = psum;
    __syncthreads();
    if ((tid & 3) == 0)
        Psq[ks*1920 + m0g + (tid >> 2)] = Ps[tid] + Ps[tid+1] + Ps[tid+2] + Ps[tid+3];
#pragma unroll
    for (int ct = 0; ct < 4; ++ct) {
        int col = ct*16 + (l & 15);
        if (col < Cc) {
#pragma unroll
            for (int i = 0; i < 4; ++i) {
                int row = m0g + w*16 + (l >> 4)*4 + i;
                P[(size_t)(ks*1920 + row)*Cc + col] = acc[ct][i];
            }
        }
    }
}

// ---------------- K_se: reduce Psq -> sq, then SE MLP -> a[b,s] ----------------
__global__ __launch_bounds__(64) void k_se(const float* __restrict__ Psq, const float* __restrict__ w1,
                                           const float* __restrict__ w2, float* __restrict__ aout)
{
    int b = threadIdx.x;
    float sv[Ss];
#pragma unroll
    for (int s = 0; s < Ss; ++s) {
        float acc = 0.f;
#pragma unroll
        for (int ks = 0; ks < KSPLIT; ++ks) acc += Psq[ks*1920 + b*Ss + s];
        sv[s] = acc / (float)CL;
    }
    float hid[15];
#pragma unroll
    for (int j = 0; j < 15; ++j) {
        float h = 0.f;
        for (int s = 0; s < Ss; ++s) h += sv[s] * w1[s*15 + j];
        hid[j] = fmaxf(h, 0.f);
    }
    for (int s = 0; s < Ss; ++s) {
        float o = 0.f;
#pragma unroll
        for (int j = 0; j < 15; ++j) o += hid[j] * w2[j*Ss + s];
        aout[b*Ss + s] = 1.f / (1.f + expf(-o));
    }
}

// ---------------- K_maxseg: rows (stride 170) ----------------
__global__ __launch_bounds__(256) void k_maxseg(const float* __restrict__ x, const float* __restrict__ a,
                                                float* __restrict__ ms)
{
    int idx = blockIdx.x * 256 + threadIdx.x;
    if (idx >= Bb*CL) return;
    int row = idx / Ll;                 // b*62 + c
    int l   = idx - row*Ll;
    int b   = row / Cc;
    int c   = row - b*Cc;
    float m = -INFINITY;
    for (int s = 0; s < Ss; ++s) {
        float v = x[(size_t)(b*Ss + s)*CL + c*Ll + l] * a[b*Ss + s];
        m = fmaxf(m, v);
    }
    ms[(size_t)row*MSS + l] = m;
}

// ---------------- K_dftg: DFT as MFMA GEMM  F[3968][338] = ms * T ----------------
__global__ __launch_bounds__(256) void k_dftg(const float* __restrict__ ms,
                                              const unsigned short* __restrict__ T,
                                              float* __restrict__ fre, float* __restrict__ fim)
{
    __shared__ __align__(16) unsigned short As[64*64];
    __shared__ __align__(16) unsigned short Bs[64*64];
    const int tid = threadIdx.x;
    const int mtile = blockIdx.x % 62;
    const int ntile = blockIdx.x / 62;             // 0..5
    const int m0 = mtile*64, n0g = ntile*64;
    const int w = tid >> 6, l = tid & 63;
    const int arow = w*16 + (l & 15);
    const int klane = (l >> 4) * 8;
    const int sr = tid >> 2, sq4 = (tid & 3) << 4;

    f32x4 acc[4];
#pragma unroll
    for (int ct = 0; ct < 4; ++ct) acc[ct] = (f32x4){0.f, 0.f, 0.f, 0.f};

    for (int kb = 0; kb < 192; kb += 64) {
        {
            const float* ap = ms + (size_t)(m0 + sr)*MSS + kb + sq4;
            unsigned short tb[16];
            if (kb + 64 <= Ll) {
#pragma unroll
                for (int t2 = 0; t2 < 8; ++t2) {
                    float2 v = *reinterpret_cast<const float2*>(ap + 2*t2);
                    tb[2*t2]   = f2bf(v.x);
                    tb[2*t2+1] = f2bf(v.y);
                }
            } else {
#pragma unroll
                for (int t = 0; t < 16; ++t) {
                    int col = kb + sq4 + t;
                    tb[t] = (col < Ll) ? f2bf(ap[t]) : (unsigned short)0;
                }
            }
            int i0 = (sr*64 + sq4)     ^ ((sr & 7) << 3);
            int i1 = (sr*64 + sq4 + 8) ^ ((sr & 7) << 3);
            short8 p0, p1;
#pragma unroll
            for (int t = 0; t < 8; ++t) { p0[t] = (short)tb[t]; p1[t] = (short)tb[t+8]; }
            *reinterpret_cast<short8*>(&As[i0]) = p0;
            *reinterpret_cast<short8*>(&As[i1]) = p1;
        }
        {
            const unsigned short* tp = T + (size_t)(n0g + sr)*192 + kb + sq4;
            short8 p0 = *reinterpret_cast<const short8*>(tp);
            short8 p1 = *reinterpret_cast<const short8*>(tp + 8);
            int i0 = (sr*64 + sq4)     ^ ((sr & 7) << 3);
            int i1 = (sr*64 + sq4 + 8) ^ ((sr & 7) << 3);
            *reinterpret_cast<short8*>(&Bs[i0]) = p0;
            *reinterpret_cast<short8*>(&Bs[i1]) = p1;
        }
        __syncthreads();
#pragma unroll
        for (int ks2 = 0; ks2 < 2; ++ks2) {
            int kk0 = ks2*32 + klane;
            int ia = (arow*64 + kk0) ^ ((arow & 7) << 3);
            short8 af = *reinterpret_cast<const short8*>(&As[ia]);
#pragma unroll
            for (int ct = 0; ct < 4; ++ct) {
                int bcol = ct*16 + (l & 15);
                int ib = (bcol*64 + kk0) ^ ((bcol & 7) << 3);
                short8 bf = *reinterpret_cast<const short8*>(&Bs[ib]);
                acc[ct] = __builtin_amdgcn_mfma_f32_16x16x32_bf16(af, bf, acc[ct], 0, 0, 0);
            }
        }
        __syncthreads();
    }
#pragma unroll
    for (int ct = 0; ct < 4; ++ct) {
        int col = n0g + ct*16 + (l & 15);
#pragma unroll
        for (int i = 0; i < 4; ++i) {
            int row = m0 + w*16 + (l >> 4)*4 + i;
            if (col < Ll)       fre[(size_t)row*Ll + col] = acc[ct][i];
            else if (col < 338) fim[(size_t)row*Ll + (col - Ll)] = acc[ct][i];
        }
    }
}

// ---------------- K_adjrow ----------------
__global__ __launch_bounds__(64) void k_adjrow(const float* __restrict__ fre, const float* __restrict__ fim,
                                               float* __restrict__ adjr)
{
    int b = blockIdx.x / Cc;
    int j = blockIdx.x % Cc;
    int lane = threadIdx.x;
    const float* re61 = fre + (size_t)(b*Cc + 61)*Ll;
    const float* im61 = fim + (size_t)(b*Cc + 61)*Ll;
    const float* rej  = fre + (size_t)(b*Cc + j)*Ll;
    const float* imj  = fim + (size_t)(b*Cc + j)*Ll;
    float num = 0.f, den = 0.f;
    for (int l = lane; l < Ll; l += 64) {
        float ar = re61[l], ai = im61[l];
        float br = rej[l],  bi = imj[l];
        num += ai*br - ar*bi;
        den += sqrtf(ar*ar + ai*ai) * sqrtf(br*br + bi*bi);
    }
    for (int off = 32; off; off >>= 1) { num += __shfl_down(num, off); den += __shfl_down(den, off); }
    if (lane == 0) adjr[b*Cc + j] = (j == 61) ? 0.f : num / den;
}

// ---------------- K_g: adj_t (inline split-K reduce) , v, g, pre-gates ----------------
__global__ __launch_bounds__(256) void k_g(const float* __restrict__ x, const float* __restrict__ P,
    const float* __restrict__ Ccst,
    const float* __restrict__ adjr, const float* __restrict__ gcn_w, const float* __restrict__ gcn_b,
    const float* __restrict__ w_r, const float* __restrict__ w_u, const float* __restrict__ w_c,
    float* __restrict__ preR, float* __restrict__ preU, float* __restrict__ preC)
{
    __shared__ float adjt[Cc];
    __shared__ float v[Ll];
    __shared__ float g[GRU];
    int bt = blockIdx.x, t = bt >> 6, b = bt & 63;
    int m = b * Ss + t;
    int tid = threadIdx.x;
    if (tid < Cc) {
        float sv = Ccst[0] + adjr[b*Cc + tid];
#pragma unroll
        for (int ks = 0; ks < KSPLIT; ++ks) sv += P[((size_t)ks*1920 + m)*Cc + tid];
        adjt[tid] = 1.f / (1.f + expf(-sv));
    }
    __syncthreads();
    if (tid < Ll) {
        const float* xp = x + (size_t)m*CL + tid;
        float acc = 0.f;
        for (int j = 0; j < Cc; ++j) acc += adjt[j] * xp[j*Ll];
        v[tid] = acc;
    }
    __syncthreads();
    if (tid < GRU) {
        float acc = gcn_b[tid];
        for (int l = 0; l < Ll; ++l) acc += v[l] * gcn_w[l*GRU + tid];
        g[tid] = acc;
    }
    __syncthreads();
    if (tid < GRU) {
        float ar = 0.f, au = 0.f, ac = 0.f;
        for (int i = 0; i < GRU; ++i) {
            float gi = g[i];
            ar += gi * w_r[i*GRU + tid];
            au += gi * w_u[i*GRU + tid];
            ac += gi * w_c[i*GRU + tid];
        }
        preR[(size_t)bt*GRU + tid] = ar;
        preU[(size_t)bt*GRU + tid] = au;
        preC[(size_t)bt*GRU + tid] = ac;
    }
}

// ---------------- K_gru: 4-wave cooperative scan ----------------
__global__ __launch_bounds__(256) void k_gru(const float* __restrict__ preR, const float* __restrict__ preU,
    const float* __restrict__ preC,
    const float* __restrict__ w_r, const float* __restrict__ wb_r,
    const float* __restrict__ w_u, const float* __restrict__ wb_u,
    const float* __restrict__ w_c, const float* __restrict__ wb_c,
    const float* __restrict__ b_r, const float* __restrict__ b_u, const float* __restrict__ b_c,
    float* __restrict__ out)
{
    __shared__ float h[GRU], rh[GRU];
    __shared__ float part[3][4][GRU];
    __shared__ float preS[Ss][3][GRU];
    const int b = blockIdx.x;
    const int t = threadIdx.x, o = t & 63, q = t >> 6;

    float wr[16], wu[16], wc[16];
#pragma unroll
    for (int i = 0; i < 16; ++i) {
        wr[i] = w_r[(GRU + q*16 + i)*GRU + o];
        wu[i] = w_u[(GRU + q*16 + i)*GRU + o];
        wc[i] = w_c[(GRU + q*16 + i)*GRU + o];
    }
    for (int u = t; u < Ss*GRU; u += 256) {
        int s = u >> 6, oo = u & 63;
        size_t base = (size_t)(s*Bb + b)*GRU + oo;
        preS[s][0][oo] = preR[base];
        preS[s][1][oo] = preU[base];
        preS[s][2][oo] = preC[base];
    }
    const float cr = wb_r[o] + b_r[o];
    const float cu = wb_u[o] + b_u[o];
    const float cc = wb_c[o] + b_c[o];
    if (t < GRU) h[t] = 0.f;
    float ug = 0.f;
    __syncthreads();

    for (int s = 0; s < Ss; ++s) {
        float ar = 0.f, au = 0.f;
#pragma unroll
        for (int i = 0; i < 16; ++i) {
            float hi = h[q*16 + i];
            ar += hi * wr[i];
            au += hi * wu[i];
        }
        part[0][q][o] = ar;
        part[1][q][o] = au;
        __syncthreads();
        if (q == 0) {
            float arf = preS[s][0][o] + cr + part[0][0][o] + part[0][1][o] + part[0][2][o] + part[0][3][o];
            float auf = preS[s][1][o] + cu + part[1][0][o] + part[1][1][o] + part[1][2][o] + part[1][3][o];
            float r = 1.f / (1.f + expf(-arf));
            ug = 1.f / (1.f + expf(-auf));
            rh[o] = r * h[o];
        }
        __syncthreads();
        float ac = 0.f;
#pragma unroll
        for (int i = 0; i < 16; ++i) ac += rh[q*16 + i] * wc[i];
        part[2][q][o] = ac;
        __syncthreads();
        if (q == 0) {
            float acf = preS[s][2][o] + cc + part[2][0][o] + part[2][1][o] + part[2][2][o] + part[2][3][o];
            float ct = tanhf(acf);
            float hn = ug * h[o] + (1.f - ug) * ct;
            h[o] = hn;
            if (s == Ss - 1) out[b*GRU + o] = hn;
        }
        __syncthreads();
    }
}

// ---------------- launcher ----------------
extern "C" void kernel_launch(void* const* d_in, const int* in_sizes, int n_in,
                              void* d_out, int out_size, void* d_ws, size_t ws_size,
                              hipStream_t stream)
{
    const float* x     = (const float*)d_in[0];
    const float* se_w1 = (const float*)d_in[1];
    const float* se_w2 = (const float*)d_in[2];
    const float* dwk1  = (const float*)d_in[3];
    const float* dwb1  = (const float*)d_in[4];
    const float* pwk1  = (const float*)d_in[5];
    const float* pwb1  = (const float*)d_in[6];
    const float* dwk2  = (const float*)d_in[7];
    const float* dwb2  = (const float*)d_in[8];
    const float* pwk2  = (const float*)d_in[9];
    const float* pwb2  = (const float*)d_in[10];
    const float* dwk3  = (const float*)d_in[11];
    const float* dwb3  = (const float*)d_in[12];
    const float* pwk3  = (const float*)d_in[13];
    const float* pwb3  = (const float*)d_in[14];
    const float* gcn_w = (const float*)d_in[15];
    const float* gcn_b = (const float*)d_in[16];
    const float* w_r   = (const float*)d_in[17];
    const float* wb_r  = (const float*)d_in[18];
    const float* w_u   = (const float*)d_in[19];
    const float* wb_u  = (const float*)d_in[20];
    const float* w_c   = (const float*)d_in[21];
    const float* wb_c  = (const float*)d_in[22];
    const float* b_r   = (const float*)d_in[23];
    const float* b_u   = (const float*)d_in[24];
    const float* b_c   = (const float*)d_in[25];
    float* out = (float*)d_out;

    // flat workspace (floats), ~17.5 MB total (ws >= 322 MB per fill evidence)
    float* ws   = (float*)d_ws;
    float* Psq  = ws;                    // 30720 (16 x 1920)
    float* aw   = Psq  + 30720;          // 1920
    float* msb  = aw   + 1920;           // 674560 (3968*170)
    float* f_re = msb  + 674560;         // 670592
    float* f_im = f_re + 670592;         // 670592
    float* adjr = f_im + 670592;         // 3968
    float* P    = adjr + 3968;           // 1904640 (16 x 1920 x 62)
    float* preR = P    + 1904640;        // 122880
    float* preU = preR + 122880;         // 122880
    float* preC = preU + 122880;         // 122880
    float* Heff = preC + 122880;         // 6696
    float* Ccst = Heff + 6696;           // 8
    float* Gbuf = Ccst + 8;              // 2790
    unsigned short* TBt = (unsigned short*)(Gbuf + 2790);   // 73728 ushorts

    k_misc<<<Cc + 1 + 288, 256, 0, stream>>>(pwk1, pwb1, dwb1, dwk2, dwb2, pwk2, pwb2,
                                             dwk3, dwb3, pwk3, pwb3, Gbuf, Ccst, TBt);
    k_h1h<<<Cc, 128, 0, stream>>>(pwk1, dwk1, Gbuf, Heff);
    k_gemm<<<30*KSPLIT, 256, 0, stream>>>(x, Heff, P, Psq);
    k_se<<<1, 64, 0, stream>>>(Psq, se_w1, se_w2, aw);
    k_maxseg<<<(Bb*CL + 255)/256, 256, 0, stream>>>(x, aw, msb);
    k_dftg<<<62*6, 256, 0, stream>>>(msb, TBt, f_re, f_im);
    k_adjrow<<<Bb*Cc, 64, 0, stream>>>(f_re, f_im, adjr);
    k_g<<<Ss*Bb, 256, 0, stream>>>(x, P, Ccst, adjr, gcn_w, gcn_b, w_r, w_u, w_c, preR, preU, preC);
    k_gru<<<Bb, 256, 0, stream>>>(preR, preU, preC, w_r, wb_r, w_u, wb_u, w_c, wb_c,
                                  b_r, b_u, b_c, out);
}

// Round 10
// 89.337 us; speedup vs baseline: 24.1014x; 1.5128x over previous
//
#include <hip/hip_runtime.h>
#include <hip/hip_bf16.h>
#include <math.h>

#define Bb 64
#define Ss 30
#define Cc 62
#define Ll 169
#define CL (Cc*Ll)          // 10478
#define GRU 64
#define HTAPS 108           // 64+32+14-2
#define KSPLIT 16
#define KSLICE 656          // 16*656 >= 10478

typedef __attribute__((ext_vector_type(8))) short short8;
typedef __attribute__((ext_vector_type(4))) float f32x4;

__device__ __forceinline__ unsigned short f2bf(float f)
{
    union { float f; unsigned int u; } v; v.f = f;
    unsigned int u = v.u + 0x7fffu + ((v.u >> 16) & 1u);   // RNE
    return (unsigned short)(u >> 16);
}

// NOTE: the reference's iCOH adjacency is mathematically zero:
// sum_k f_i[k]*conj(f_j[k]) = L * sum_n x_i[n] x_j[n]  (Parseval, real x)
// => Im part == 0 => num == 0 => adj == 0 (diagonal masked anyway).
// The SE / max_seg / FFT branch therefore contributes nothing and is elided.

// ---------------- K_misc: blk<62 -> fg(e=blk); blk==62 -> bias constant C ----------------
__global__ __launch_bounds__(256) void k_misc(
    const float* __restrict__ pwk1, const float* __restrict__ pwb1, const float* __restrict__ dwb1,
    const float* __restrict__ dwk2, const float* __restrict__ dwb2,
    const float* __restrict__ pwk2, const float* __restrict__ pwb2,
    const float* __restrict__ dwk3, const float* __restrict__ dwb3,
    const float* __restrict__ pwk3, const float* __restrict__ pwb3,
    float* __restrict__ Gout, float* __restrict__ Ccst)
{
    __shared__ float s0[Cc], s1[Cc], s2[Cc], F[14], k2[32];
    const int blk = blockIdx.x, t = threadIdx.x;
    if (blk < Cc) {
        // F[e][t] = sum_f pwk3[61,f]*pwk2[f,e]*dwk3[f,t];  G[e] = F conv dwk2[e]
        const int e = blk;
        if (t < Cc) { s0[t] = pwk3[61*Cc + t]; s1[t] = pwk2[t*Cc + e]; }
        if (t < 32) k2[t] = dwk2[e*32 + t];
        __syncthreads();
        if (t < 14) {
            float acc = 0.f;
            for (int f = 0; f < Cc; ++f) acc += s0[f] * s1[f] * dwk3[f*14 + t];
            F[t] = acc;
        }
        __syncthreads();
        if (t < 45) {
            float acc = 0.f;
            int t0 = t - 31; if (t0 < 0) t0 = 0;
            int t1 = t; if (t1 > 13) t1 = 13;
            for (int tt = t0; tt <= t1; ++tt) acc += F[tt] * k2[t - tt];
            Gout[e*45 + t] = acc;
        }
    } else {
        // bias constant C
        if (t < Cc) s0[t] = dwb1[t];
        __syncthreads();
        if (t < Cc) {
            float acc = pwb1[t];
            for (int c = 0; c < Cc; ++c) acc += pwk1[t*Cc + c] * s0[c];
            float sk = 0.f;
            for (int a = 0; a < 32; ++a) sk += dwk2[t*32 + a];
            s1[t] = acc * sk + dwb2[t];
        }
        __syncthreads();
        if (t < Cc) {
            float acc = pwb2[t];
            for (int e = 0; e < Cc; ++e) acc += pwk2[t*Cc + e] * s1[e];
            float sk = 0.f;
            for (int tt = 0; tt < 14; ++tt) sk += dwk3[t*14 + tt];
            s2[t] = acc * sk + dwb3[t];
        }
        __syncthreads();
        if (t < 64) {
            float v = (t < Cc) ? pwk3[61*Cc + t] * s2[t] : 0.f;
            for (int off = 32; off; off >>= 1) v += __shfl_down(v, off);
            if (t == 0) Ccst[0] = v + pwb3[61];
        }
    }
}

// ---------------- K_h1h: per-c H1 then Heff (62 blocks) ----------------
__global__ __launch_bounds__(128) void k_h1h(const float* __restrict__ pwk1, const float* __restrict__ dwk1,
                                             const float* __restrict__ Gin, float* __restrict__ Heff)
{
    __shared__ float p1c[Cc], H1[45], k1[64];
    int c = blockIdx.x, t = threadIdx.x;
    if (t < Cc) p1c[t] = pwk1[t*Cc + c];
    if (t >= 64 && t < 128) k1[t - 64] = dwk1[c*64 + (t - 64)];
    __syncthreads();
    if (t < 45) {
        float acc = 0.f;
        for (int e = 0; e < Cc; ++e) acc += p1c[e] * Gin[e*45 + t];
        H1[t] = acc;
    }
    __syncthreads();
    if (t < HTAPS) {
        float acc = 0.f;
        int s0 = t - 63; if (s0 < 0) s0 = 0;
        int s1 = t; if (s1 > 44) s1 = 44;
        for (int s = s0; s <= s1; ++s) acc += H1[s] * k1[t - s];
        Heff[c*HTAPS + t] = acc;
    }
}

// ---------------- K_gemm: MFMA  P[ks][1920][62] = X*H (bf16) ----------------
__global__ __launch_bounds__(256) void k_gemm(const float* __restrict__ x,
                                              const float* __restrict__ Heff,
                                              float* __restrict__ P)
{
    __shared__ __align__(16) unsigned short Xs[64*64];
    __shared__ __align__(16) unsigned short Hs[64*64];
    const int tid = threadIdx.x;
    const int mt = blockIdx.x % 30;
    const int ks = blockIdx.x / 30;
    const int k0 = ks * KSLICE;
    const int kend = (k0 + KSLICE < CL) ? (k0 + KSLICE) : CL;
    const int m0g = mt * 64;
    const int w = tid >> 6, l = tid & 63;
    const int arow = w*16 + (l & 15);
    const int klane = (l >> 4) * 8;
    const int sr = tid >> 2, sq4 = (tid & 3) << 4;

    f32x4 acc[4];
#pragma unroll
    for (int ct = 0; ct < 4; ++ct) acc[ct] = (f32x4){0.f, 0.f, 0.f, 0.f};

    for (int kb = k0; kb < kend; kb += 64) {
        {
            const float* xp = x + (size_t)(m0g + sr)*CL + kb + sq4;
            unsigned short tb[16];
            if (kb + 64 <= kend) {
#pragma unroll
                for (int t2 = 0; t2 < 8; ++t2) {
                    float2 v = *reinterpret_cast<const float2*>(xp + 2*t2);
                    tb[2*t2]   = f2bf(v.x);
                    tb[2*t2+1] = f2bf(v.y);
                }
            } else {
#pragma unroll
                for (int t = 0; t < 16; ++t) {
                    int col = kb + sq4 + t;
                    tb[t] = f2bf((col < kend) ? xp[t] : 0.f);
                }
            }
            int i0 = (sr*64 + sq4)     ^ ((sr & 7) << 3);
            int i1 = (sr*64 + sq4 + 8) ^ ((sr & 7) << 3);
            short8 p0, p1;
#pragma unroll
            for (int t = 0; t < 8; ++t) { p0[t] = (short)tb[t]; p1[t] = (short)tb[t+8]; }
            *reinterpret_cast<short8*>(&Xs[i0]) = p0;
            *reinterpret_cast<short8*>(&Xs[i1]) = p1;
        }
        {
            int j = sr;
            unsigned short tb[16];
#pragma unroll
            for (int t = 0; t < 16; ++t) {
                int kg = kb + sq4 + t;
                float hv = 0.f;
                if (kg < kend && j < Cc) {
                    int c = kg / Ll, ll = kg - c*Ll;
                    int a = ll - j;
                    if (a >= 0 && a < HTAPS) hv = Heff[c*HTAPS + a];
                }
                tb[t] = f2bf(hv);
            }
            int i0 = (j*64 + sq4)     ^ ((j & 7) << 3);
            int i1 = (j*64 + sq4 + 8) ^ ((j & 7) << 3);
            short8 p0, p1;
#pragma unroll
            for (int t = 0; t < 8; ++t) { p0[t] = (short)tb[t]; p1[t] = (short)tb[t+8]; }
            *reinterpret_cast<short8*>(&Hs[i0]) = p0;
            *reinterpret_cast<short8*>(&Hs[i1]) = p1;
        }
        __syncthreads();
#pragma unroll
        for (int ks2 = 0; ks2 < 2; ++ks2) {
            int kk0 = ks2*32 + klane;
            int ia = (arow*64 + kk0) ^ ((arow & 7) << 3);
            short8 af = *reinterpret_cast<const short8*>(&Xs[ia]);
#pragma unroll
            for (int ct = 0; ct < 4; ++ct) {
                int bcol = ct*16 + (l & 15);
                int ib = (bcol*64 + kk0) ^ ((bcol & 7) << 3);
                short8 bf = *reinterpret_cast<const short8*>(&Hs[ib]);
                acc[ct] = __builtin_amdgcn_mfma_f32_16x16x32_bf16(af, bf, acc[ct], 0, 0, 0);
            }
        }
        __syncthreads();
    }
#pragma unroll
    for (int ct = 0; ct < 4; ++ct) {
        int col = ct*16 + (l & 15);
        if (col < Cc) {
#pragma unroll
            for (int i = 0; i < 4; ++i) {
                int row = m0g + w*16 + (l >> 4)*4 + i;
                P[(size_t)(ks*1920 + row)*Cc + col] = acc[ct][i];
            }
        }
    }
}

// ---------------- K_g: adj_t = sigmoid(C + sum_ks P) , v, g, pre-gates ----------------
__global__ __launch_bounds__(256) void k_g(const float* __restrict__ x, const float* __restrict__ P,
    const float* __restrict__ Ccst,
    const float* __restrict__ gcn_w, const float* __restrict__ gcn_b,
    const float* __restrict__ w_r, const float* __restrict__ w_u, const float* __restrict__ w_c,
    float* __restrict__ preR, float* __restrict__ preU, float* __restrict__ preC)
{
    __shared__ float adjt[Cc];
    __shared__ float v[Ll];
    __shared__ float g[GRU];
    int bt = blockIdx.x, t = bt >> 6, b = bt & 63;
    int m = b * Ss + t;
    int tid = threadIdx.x;
    if (tid < Cc) {
        float sv = Ccst[0];
#pragma unroll
        for (int ks = 0; ks < KSPLIT; ++ks) sv += P[((size_t)ks*1920 + m)*Cc + tid];
        adjt[tid] = 1.f / (1.f + expf(-sv));
    }
    __syncthreads();
    if (tid < Ll) {
        const float* xp = x + (size_t)m*CL + tid;
        float acc = 0.f;
        for (int j = 0; j < Cc; ++j) acc += adjt[j] * xp[j*Ll];
        v[tid] = acc;
    }
    __syncthreads();
    if (tid < GRU) {
        float acc = gcn_b[tid];
        for (int l = 0; l < Ll; ++l) acc += v[l] * gcn_w[l*GRU + tid];
        g[tid] = acc;
    }
    __syncthreads();
    if (tid < GRU) {
        float ar = 0.f, au = 0.f, ac = 0.f;
        for (int i = 0; i < GRU; ++i) {
            float gi = g[i];
            ar += gi * w_r[i*GRU + tid];
            au += gi * w_u[i*GRU + tid];
            ac += gi * w_c[i*GRU + tid];
        }
        preR[(size_t)bt*GRU + tid] = ar;
        preU[(size_t)bt*GRU + tid] = au;
        preC[(size_t)bt*GRU + tid] = ac;
    }
}

// ---------------- K_gru: 4-wave cooperative scan ----------------
__global__ __launch_bounds__(256) void k_gru(const float* __restrict__ preR, const float* __restrict__ preU,
    const float* __restrict__ preC,
    const float* __restrict__ w_r, const float* __restrict__ wb_r,
    const float* __restrict__ w_u, const float* __restrict__ wb_u,
    const float* __restrict__ w_c, const float* __restrict__ wb_c,
    const float* __restrict__ b_r, const float* __restrict__ b_u, const float* __restrict__ b_c,
    float* __restrict__ out)
{
    __shared__ float h[GRU], rh[GRU];
    __shared__ float part[3][4][GRU];
    __shared__ float preS[Ss][3][GRU];
    const int b = blockIdx.x;
    const int t = threadIdx.x, o = t & 63, q = t >> 6;

    float wr[16], wu[16], wc[16];
#pragma unroll
    for (int i = 0; i < 16; ++i) {
        wr[i] = w_r[(GRU + q*16 + i)*GRU + o];
        wu[i] = w_u[(GRU + q*16 + i)*GRU + o];
        wc[i] = w_c[(GRU + q*16 + i)*GRU + o];
    }
    for (int u = t; u < Ss*GRU; u += 256) {
        int s = u >> 6, oo = u & 63;
        size_t base = (size_t)(s*Bb + b)*GRU + oo;
        preS[s][0][oo] = preR[base];
        preS[s][1][oo] = preU[base];
        preS[s][2][oo] = preC[base];
    }
    const float cr = wb_r[o] + b_r[o];
    const float cu = wb_u[o] + b_u[o];
    const float cc = wb_c[o] + b_c[o];
    if (t < GRU) h[t] = 0.f;
    float ug = 0.f;
    __syncthreads();

    for (int s = 0; s < Ss; ++s) {
        float ar = 0.f, au = 0.f;
#pragma unroll
        for (int i = 0; i < 16; ++i) {
            float hi = h[q*16 + i];
            ar += hi * wr[i];
            au += hi * wu[i];
        }
        part[0][q][o] = ar;
        part[1][q][o] = au;
        __syncthreads();
        if (q == 0) {
            float arf = preS[s][0][o] + cr + part[0][0][o] + part[0][1][o] + part[0][2][o] + part[0][3][o];
            float auf = preS[s][1][o] + cu + part[1][0][o] + part[1][1][o] + part[1][2][o] + part[1][3][o];
            float r = 1.f / (1.f + expf(-arf));
            ug = 1.f / (1.f + expf(-auf));
            rh[o] = r * h[o];
        }
        __syncthreads();
        float ac = 0.f;
#pragma unroll
        for (int i = 0; i < 16; ++i) ac += rh[q*16 + i] * wc[i];
        part[2][q][o] = ac;
        __syncthreads();
        if (q == 0) {
            float acf = preS[s][2][o] + cc + part[2][0][o] + part[2][1][o] + part[2][2][o] + part[2][3][o];
            float ct = tanhf(acf);
            float hn = ug * h[o] + (1.f - ug) * ct;
            h[o] = hn;
            if (s == Ss - 1) out[b*GRU + o] = hn;
        }
        __syncthreads();
    }
}

// ---------------- launcher ----------------
extern "C" void kernel_launch(void* const* d_in, const int* in_sizes, int n_in,
                              void* d_out, int out_size, void* d_ws, size_t ws_size,
                              hipStream_t stream)
{
    const float* x     = (const float*)d_in[0];
    const float* dwk1  = (const float*)d_in[3];
    const float* dwb1  = (const float*)d_in[4];
    const float* pwk1  = (const float*)d_in[5];
    const float* pwb1  = (const float*)d_in[6];
    const float* dwk2  = (const float*)d_in[7];
    const float* dwb2  = (const float*)d_in[8];
    const float* pwk2  = (const float*)d_in[9];
    const float* pwb2  = (const float*)d_in[10];
    const float* dwk3  = (const float*)d_in[11];
    const float* dwb3  = (const float*)d_in[12];
    const float* pwk3  = (const float*)d_in[13];
    const float* pwb3  = (const float*)d_in[14];
    const float* gcn_w = (const float*)d_in[15];
    const float* gcn_b = (const float*)d_in[16];
    const float* w_r   = (const float*)d_in[17];
    const float* wb_r  = (const float*)d_in[18];
    const float* w_u   = (const float*)d_in[19];
    const float* wb_u  = (const float*)d_in[20];
    const float* w_c   = (const float*)d_in[21];
    const float* wb_c  = (const float*)d_in[22];
    const float* b_r   = (const float*)d_in[23];
    const float* b_u   = (const float*)d_in[24];
    const float* b_c   = (const float*)d_in[25];
    float* out = (float*)d_out;

    // flat workspace (floats), ~9.4 MB
    float* ws   = (float*)d_ws;
    float* P    = ws;                    // 1904640 (16 x 1920 x 62)
    float* preR = P    + 1904640;        // 122880
    float* preU = preR + 122880;         // 122880
    float* preC = preU + 122880;         // 122880
    float* Heff = preC + 122880;         // 6696
    float* Ccst = Heff + 6696;           // 8
    float* Gbuf = Ccst + 8;              // 2790

    k_misc<<<Cc + 1, 256, 0, stream>>>(pwk1, pwb1, dwb1, dwk2, dwb2, pwk2, pwb2,
                                       dwk3, dwb3, pwk3, pwb3, Gbuf, Ccst);
    k_h1h<<<Cc, 128, 0, stream>>>(pwk1, dwk1, Gbuf, Heff);
    k_gemm<<<30*KSPLIT, 256, 0, stream>>>(x, Heff, P);
    k_g<<<Ss*Bb, 256, 0, stream>>>(x, P, Ccst, gcn_w, gcn_b, w_r, w_u, w_c, preR, preU, preC);
    k_gru<<<Bb, 256, 0, stream>>>(preR, preU, preC, w_r, wb_r, w_u, wb_u, w_c, wb_c,
                                  b_r, b_u, b_c, out);
}